// Round 8
// baseline (915.697 us; speedup 1.0000x reference)
//
#include <hip/hip_runtime.h>
#include <hip/hip_bf16.h>
#include <math.h>

typedef __bf16 bf16;
typedef __bf16 v8bf __attribute__((ext_vector_type(8)));
typedef float f32x4 __attribute__((ext_vector_type(4)));

// async global->LDS, 16B per lane (per-thread LDS offset is t*16, lane-linear).
#define GLDS16(g, l) __builtin_amdgcn_global_load_lds( \
    (const __attribute__((address_space(1))) void*)(g), \
    (__attribute__((address_space(3))) void*)(l), 16, 0, 0)

// bijective XCD-chunk swizzle (m204 variant, works for any nwg)
__device__ __forceinline__ int xcd_swz(int bid, int nwg) {
  int xcd = bid & 7, off = bid >> 3;
  int q = nwg >> 3, r = nwg & 7;
  return (xcd < r ? xcd * (q + 1) : r * (q + 1) + (xcd - r) * q) + off;
}

// ===========================================================================
// 256x128 MFMA core, BK=32: LDS slot = [A 16KB][B 8KB]; A = [128 lds-rows]
// [128B], lds-row r packs A-rows (r, r+128) (64B of k each); B = [64 rows]
// [128B] packing B-rows (r, r+64). XOR swizzle: phys col = logical^((row&7)<<4).
// 256 thr = 4 waves (2M x 2N), per-wave out 128x64: 32 MFMA / 12 ds_read_b128.
// MFMA C/D: col=lane&15, row=4*(lane>>4)+reg.
// ===========================================================================
#define RING_COMPUTE_P(SP) do { \
  v8bf b_[4], a_[4]; \
  _Pragma("unroll") for (int _j = 0; _j < 4; ++_j) { \
    int _lr = _j * 16 + l15; \
    int _c = (wn * 64 + colb) ^ ((_lr & 7) << 4); \
    b_[_j] = *(const v8bf*)((SP) + 16384 + _lr * 128 + _c); } \
  _Pragma("unroll") for (int _i = 0; _i < 4; ++_i) { \
    int _lr = _i * 16 + l15; \
    int _c = (wm * 64 + colb) ^ ((_lr & 7) << 4); \
    a_[_i] = *(const v8bf*)((SP) + _lr * 128 + _c); } \
  __builtin_amdgcn_s_setprio(1); \
  _Pragma("unroll") for (int _i = 0; _i < 4; ++_i) \
  _Pragma("unroll") for (int _j = 0; _j < 4; ++_j) \
    acc[_i][_j] = __builtin_amdgcn_mfma_f32_16x16x32_bf16(a_[_i], b_[_j], acc[_i][_j], 0, 0, 0); \
  __builtin_amdgcn_s_setprio(0); \
  _Pragma("unroll") for (int _i = 0; _i < 4; ++_i) { \
    int _lr = (_i + 4) * 16 + l15; \
    int _c = (wm * 64 + colb) ^ ((_lr & 7) << 4); \
    a_[_i] = *(const v8bf*)((SP) + _lr * 128 + _c); } \
  __builtin_amdgcn_s_setprio(1); \
  _Pragma("unroll") for (int _i = 0; _i < 4; ++_i) \
  _Pragma("unroll") for (int _j = 0; _j < 4; ++_j) \
    acc[_i + 4][_j] = __builtin_amdgcn_mfma_f32_16x16x32_bf16(a_[_i], b_[_j], acc[_i + 4][_j], 0, 0, 0); \
  __builtin_amdgcn_s_setprio(0); \
} while (0)

#define RING_COMPUTE() RING_COMPUTE_P(s0)

// ring-3 pipeline for pure-gload_lds kernels (conv_rsize / conv_qkv):
// 6 gloads/group, vmcnt(12) = 2 groups in flight; tail 6 -> 0.
#define RING_LOOP(NG, STAGE) do { \
  STAGE(0, s0); STAGE(1, s1); \
  for (int g = 0; g < (NG); ++g) { \
    if (g + 2 < (NG)) { STAGE(g + 2, s2); } \
    if (g + 2 < (NG))       asm volatile("s_waitcnt vmcnt(12)" ::: "memory"); \
    else if (g + 2 == (NG)) asm volatile("s_waitcnt vmcnt(6)" ::: "memory"); \
    else                    asm volatile("s_waitcnt vmcnt(0)" ::: "memory"); \
    __builtin_amdgcn_s_barrier(); \
    __builtin_amdgcn_sched_barrier(0); \
    RING_COMPUTE(); \
    __builtin_amdgcn_sched_barrier(0); \
    __builtin_amdgcn_s_barrier(); \
    char* _tmp = s0; s0 = s1; s1 = s2; s2 = _tmp; \
  } \
} while (0)

// ---------------------------------------------------------------------------
// G1-fused: 1x1 reduce conv + ReLU, reading interact (n,2304,256) f32
// DIRECTLY (no A1 round trip). bx = image n (M-tile 256 = its 256 pixels).
// A-stage: thread t owns linear LDS granule (i*4096+t*16) = row r=i*32+tr,
// slot s8=t&7 -> logical lb=(s8<<4)^((tr&7)<<4), hi=lb>>6, j8=(lb>>4)&3 ->
// loads 8 f32 interact[n][kt*32+j8*8+e][i*32+tr+hi*128], cvt, one
// ds_write_b128 (linear, conflict-free). B: wrb bf16 via 2 gload_lds.
// Dbuf pipeline: cvt+write(g); issue A(g+1) regs + B(g+1) glds;
// lgkmcnt(0)+vmcnt(34) retires exactly B(g) (2+32+2=36 outstanding -> 34).
// ---------------------------------------------------------------------------
__global__ __launch_bounds__(256, 2)
void k_gemm_reduce_f(const float* __restrict__ interact, const bf16* __restrict__ Bw,
                     bf16* __restrict__ f1)
{
  __shared__ __attribute__((aligned(16))) char lds[49152];
  const int s = xcd_swz(blockIdx.x, gridDim.x);   // 512 blocks
  const int by = s & 3, n = s >> 2;
  const int t = threadIdx.x, lane = t & 63, w = t >> 6;
  const int wm = w >> 1, wn = w & 1;
  const int l15 = lane & 15, colb = (lane >> 4) << 4;
  const int tr = t >> 3, s8 = t & 7;
  const int lb = (s8 << 4) ^ ((tr & 7) << 4);
  const int hi = lb >> 6, j8 = (lb >> 4) & 3;
  const int t16 = t * 16;
  const float* abase = interact + (size_t)n * 589824 + (size_t)(j8 * 8) * 256 + tr + hi * 128;
  const char* pb[2];
  #pragma unroll
  for (int i = 0; i < 2; ++i)
    pb[i] = (const char*)Bw + (size_t)(by * 128 + i * 32 + tr + hi * 64) * 4608 + (lb & 63);

  float ar[4][8];
  #define ALOAD_R(kt) do { \
    const float* _ab = abase + (size_t)(kt) * 8192; \
    _Pragma("unroll") for (int _i = 0; _i < 4; ++_i) \
    _Pragma("unroll") for (int _e = 0; _e < 8; ++_e) \
      ar[_i][_e] = _ab[_e * 256 + _i * 32]; } while (0)
  #define AWRITE_R(dst) do { \
    _Pragma("unroll") for (int _i = 0; _i < 4; ++_i) { \
      v8bf _o; \
      _Pragma("unroll") for (int _e = 0; _e < 8; ++_e) _o[_e] = (bf16)ar[_i][_e]; \
      *(v8bf*)((dst) + _i * 4096 + t16) = _o; } } while (0)
  #define BGLDS_R(kt, dst) do { \
    GLDS16(pb[0] + (size_t)(kt) * 64, (dst) + 16384 + t16); \
    GLDS16(pb[1] + (size_t)(kt) * 64, (dst) + 16384 + 4096 + t16); } while (0)

  f32x4 acc[8][4] = {};
  ALOAD_R(0);
  BGLDS_R(0, lds);
  int cur = 0;
  for (int g = 0; g < 72; ++g) {
    char* scur = lds + cur * 24576;
    AWRITE_R(scur);                               // auto vmcnt wait for ar regs
    __builtin_amdgcn_sched_barrier(0);
    if (g + 1 < 72) { ALOAD_R(g + 1); BGLDS_R(g + 1, lds + (cur ^ 1) * 24576); }
    if (g + 1 < 72) asm volatile("s_waitcnt lgkmcnt(0) vmcnt(34)" ::: "memory");
    else            asm volatile("s_waitcnt lgkmcnt(0) vmcnt(0)" ::: "memory");
    __builtin_amdgcn_s_barrier();
    __builtin_amdgcn_sched_barrier(0);
    RING_COMPUTE_P(scur);
    __builtin_amdgcn_sched_barrier(0);
    __builtin_amdgcn_s_barrier();
    cur ^= 1;
  }
  const int rbase = (lane >> 4) << 2, cl = lane & 15;
  #pragma unroll
  for (int i = 0; i < 8; ++i)
    #pragma unroll
    for (int j = 0; j < 4; ++j)
      #pragma unroll
      for (int r = 0; r < 4; ++r) {
        int row = n * 256 + wm * 128 + i * 16 + rbase + r;
        int col = by * 128 + wn * 64 + j * 16 + cl;
        f1[(size_t)row * 512 + col] = (bf16)fmaxf(acc[i][j][r], 0.f);
      }
}

// ---------------------------------------------------------------------------
// G2: 3x3 VALID conv (16x16 -> 14x14). f1 NHWC bf16 -> f14 NHWC bf16.
// M=25088 (98 bx) x 4 by = 392 blocks. Groups: 144 (9 taps x 16).
// ---------------------------------------------------------------------------
__global__ __launch_bounds__(256, 2)
void k_conv_rsize(const bf16* __restrict__ f1, const bf16* __restrict__ wt,
                  bf16* __restrict__ f14)
{
  __shared__ __attribute__((aligned(16))) char lds[73728];
  char *s0 = lds, *s1 = lds + 24576, *s2 = lds + 49152;
  const int s = xcd_swz(blockIdx.x, gridDim.x);
  const int by = s & 3, bx = s >> 2;
  const int t = threadIdx.x, lane = t & 63, w = t >> 6;
  const int wm = w >> 1, wn = w & 1;
  const int l15 = lane & 15, colb = (lane >> 4) << 4;
  const int tr = t >> 3;
  const int lb = ((t & 7) << 4) ^ ((tr & 7) << 4);
  const int hi = lb >> 6, kb = lb & 63;
  const int t16 = t * 16;
  int abase[4]; const char* pb[2];
  #pragma unroll
  for (int i = 0; i < 4; ++i) {
    int m = bx * 256 + i * 32 + tr + hi * 128;
    int n = m / 196, rem = m - n * 196;
    int y = rem / 14, x = rem - 14 * (rem / 14);
    abase[i] = n * 256 + y * 16 + x;
  }
  #pragma unroll
  for (int i = 0; i < 2; ++i)
    pb[i] = (const char*)wt + (size_t)(by * 128 + i * 32 + tr + hi * 64) * 1024 + kb;
  const char* f1c = (const char*)f1 + kb;
  #define SC(kt, ring) do { int _tap = (kt) >> 4, _ko = ((kt) & 15) << 6; \
    int _dy = (_tap * 11) >> 5, _dx = _tap - _dy * 3; \
    int _df = (_dy * 16 + _dx) << 10; \
    _Pragma("unroll") for (int _i = 0; _i < 4; ++_i) \
      GLDS16(f1c + ((size_t)abase[_i] << 10) + _df + _ko, (ring) + _i * 4096 + t16); \
    _Pragma("unroll") for (int _i = 0; _i < 2; ++_i) \
      GLDS16(pb[_i] + (size_t)_tap * 524288 + _ko, (ring) + 16384 + _i * 4096 + t16); } while (0)
  f32x4 acc[8][4] = {};
  RING_LOOP(144, SC);
  const int rbase = (lane >> 4) << 2, cl = lane & 15;
  #pragma unroll
  for (int i = 0; i < 8; ++i)
    #pragma unroll
    for (int j = 0; j < 4; ++j)
      #pragma unroll
      for (int r = 0; r < 4; ++r) {
        int row = bx * 256 + wm * 128 + i * 16 + rbase + r;
        int col = by * 128 + wn * 64 + j * 16 + cl;
        f14[(size_t)row * 512 + col] = (bf16)acc[i][j][r];
      }
}

// ---------------------------------------------------------------------------
// G4: fused q/k/v 3x3 SAME conv on 7x7. M=6272 (25 bx, masked tail) x
// 12 (tensor x by) = 300 conv blocks; blocks 300..2347 = obm mean (overlaps
// bbox HBM reads with qkv compute). Groups: 144.
// ---------------------------------------------------------------------------
__global__ __launch_bounds__(256, 2)
void k_conv_qkv(const bf16* __restrict__ fin, const bf16* __restrict__ wt,
                bf16* __restrict__ qkv, const bf16* __restrict__ zp,
                const float* __restrict__ bbox, float* __restrict__ obm)
{
  __shared__ __attribute__((aligned(16))) char lds[73728];
  char *s0 = lds, *s1 = lds + 24576, *s2 = lds + 49152;
  const int t = threadIdx.x;
  if (blockIdx.x >= 300) {
    int bid = blockIdx.x - 300;           // 2048 blocks: 128 n x 16 cgroups
    int n = bid >> 4;
    int c = (bid & 15) * 64 + (t >> 2);
    int seg = t & 3;
    const float4* p4 = (const float4*)(bbox + ((size_t)n * 1024 + c) * 196);
    float sum = 0.f;
    for (int k = seg; k < 49; k += 4) { float4 ww = p4[k]; sum += ww.x + ww.y + ww.z + ww.w; }
    sum += __shfl_xor(sum, 1);
    sum += __shfl_xor(sum, 2);
    if (seg == 0) obm[n * 1024 + c] = sum * (1.f / 196.f);
    return;
  }
  const int s = xcd_swz(blockIdx.x, 300);
  const int q12 = s % 12, bx = s / 12;
  const int tensor = q12 >> 2, byl = q12 & 3;
  const char* wtc = (const char*)wt + (size_t)tensor * 4718592;
  bf16* outp = qkv + (size_t)tensor * 3211264;
  const int lane = t & 63, w = t >> 6;
  const int wm = w >> 1, wn = w & 1;
  const int l15 = lane & 15, colb = (lane >> 4) << 4;
  const int tr = t >> 3;
  const int lb = ((t & 7) << 4) ^ ((tr & 7) << 4);
  const int hi = lb >> 6, kb = lb & 63;
  const int t16 = t * 16;
  int nb[4], py[4], px[4]; const char* pb[2];
  #pragma unroll
  for (int i = 0; i < 4; ++i) {
    int m = bx * 256 + i * 32 + tr + hi * 128;
    if (m > 6271) m = 6271;
    int n = m / 49, rem = m - n * 49;
    nb[i] = n * 49;
    py[i] = rem / 7 - 1;
    px[i] = rem - 7 * (rem / 7) - 1;
  }
  #pragma unroll
  for (int i = 0; i < 2; ++i)
    pb[i] = wtc + (size_t)(byl * 128 + i * 32 + tr + hi * 64) * 1024 + kb;
  const char* finc = (const char*)fin + kb;
  const char* zpc = (const char*)zp;
  #define SQ(kt, ring) do { int _tap = (kt) >> 4, _ko = ((kt) & 15) << 6; \
    int _dy = (_tap * 11) >> 5, _dx = _tap - _dy * 3; \
    _Pragma("unroll") for (int _i = 0; _i < 4; ++_i) { \
      int _iy = py[_i] + _dy, _ix = px[_i] + _dx; \
      const char* _sp = ((unsigned)_iy < 7u && (unsigned)_ix < 7u) \
          ? finc + (size_t)(nb[_i] + _iy * 7 + _ix) * 1024 + _ko : zpc; \
      GLDS16(_sp, (ring) + _i * 4096 + t16); } \
    _Pragma("unroll") for (int _i = 0; _i < 2; ++_i) \
      GLDS16(pb[_i] + (size_t)_tap * 524288 + _ko, (ring) + 16384 + _i * 4096 + t16); } while (0)
  f32x4 acc[8][4] = {};
  RING_LOOP(144, SQ);
  const int rbase = (lane >> 4) << 2, cl = lane & 15;
  #pragma unroll
  for (int i = 0; i < 8; ++i)
    #pragma unroll
    for (int j = 0; j < 4; ++j)
      #pragma unroll
      for (int r = 0; r < 4; ++r) {
        int row = bx * 256 + wm * 128 + i * 16 + rbase + r;
        if (row < 6272) {
          int col = byl * 128 + wn * 64 + j * 16 + cl;
          outp[(size_t)row * 512 + col] = (bf16)acc[i][j][r];
        }
      }
}

// ===========================================================================
// Old 128x128 core (kept for the tiny gemm_s)
// ===========================================================================
__device__ __forceinline__ void tile_compute(const char* ldsA, const char* ldsB,
                                             f32x4 (&acc)[4][4], int wr, int wc, int lane) {
  const int l15 = lane & 15;
  const int colb = (lane >> 4) << 4;
  #pragma unroll
  for (int kk = 0; kk < 2; ++kk) {
    v8bf a[4], b[4];
    #pragma unroll
    for (int i = 0; i < 4; ++i) {
      int ra = wr * 64 + i * 16 + l15;
      int ca = ((kk << 6) | colb) ^ ((ra & 7) << 4);
      a[i] = *(const v8bf*)(ldsA + ra * 128 + ca);
    }
    #pragma unroll
    for (int j = 0; j < 4; ++j) {
      int rb = wc * 64 + j * 16 + l15;
      int cb = ((kk << 6) | colb) ^ ((rb & 7) << 4);
      b[j] = *(const v8bf*)(ldsB + rb * 128 + cb);
    }
    __builtin_amdgcn_s_setprio(1);
    #pragma unroll
    for (int i = 0; i < 4; ++i)
      #pragma unroll
      for (int j = 0; j < 4; ++j)
        acc[i][j] = __builtin_amdgcn_mfma_f32_16x16x32_bf16(a[i], b[j], acc[i][j], 0, 0, 0);
    __builtin_amdgcn_s_setprio(0);
  }
}

#define PIPELINE_LOOP(NK)                                                   \
  stage(0, lds);                                                            \
  stage(1, lds + 32768);                                                    \
  int cur = 0;                                                              \
  for (int ks = 0; ks < (NK) - 1; ++ks) {                                   \
    asm volatile("s_waitcnt vmcnt(8)" ::: "memory");                        \
    __builtin_amdgcn_s_barrier();                                           \
    __builtin_amdgcn_sched_barrier(0);                                      \
    tile_compute(lds + cur * 32768, lds + cur * 32768 + 16384, acc, wr, wc, lane); \
    __builtin_amdgcn_sched_barrier(0);                                      \
    __builtin_amdgcn_s_barrier();                                           \
    __builtin_amdgcn_sched_barrier(0);                                      \
    if (ks + 2 < (NK)) stage(ks + 2, lds + cur * 32768);                    \
    cur ^= 1;                                                               \
  }                                                                         \
  asm volatile("s_waitcnt vmcnt(0)" ::: "memory");                          \
  __builtin_amdgcn_s_barrier();                                             \
  __builtin_amdgcn_sched_barrier(0);                                        \
  tile_compute(lds + cur * 32768, lds + cur * 32768 + 16384, acc, wr, wc, lane);

// G6: w1-conv+ho-mean GEMM, K-split: part[ks] = A_s[:,ksK] @ w1r[:,ksK]^T.
__global__ __launch_bounds__(256)
void k_gemm_s(const bf16* __restrict__ A_s, const bf16* __restrict__ w1r,
              float* __restrict__ part)
{
  __shared__ __attribute__((aligned(16))) char lds[65536];
  const int by = blockIdx.x, kspl = blockIdx.y;
  const int t = threadIdx.x, lane = t & 63, w = t >> 6, wr = w >> 1, wc = w & 1;
  const int tr = t >> 3;
  const int cphys = ((t & 7) << 4) ^ ((tr & 7) << 4);
  const char* pa[4]; const char* pb[4];
  #pragma unroll
  for (int i = 0; i < 4; ++i) {
    int r = i * 32 + tr;
    pa[i] = (const char*)A_s + (size_t)r * 9216 + kspl * 2304 + cphys;
    pb[i] = (const char*)w1r + (size_t)(by * 128 + r) * 9216 + kspl * 2304 + cphys;
  }
  const int lo = t * 16;
  auto stage = [&](int ks, char* base) {
    #pragma unroll
    for (int i = 0; i < 4; ++i) GLDS16(pa[i] + ks * 128, base + lo + i * 4096);
    #pragma unroll
    for (int i = 0; i < 4; ++i) GLDS16(pb[i] + ks * 128, base + 16384 + lo + i * 4096);
  };
  f32x4 acc[4][4] = {};
  PIPELINE_LOOP(18)
  const int rb = (lane >> 4) << 2, cl = lane & 15;
  #pragma unroll
  for (int i = 0; i < 4; ++i)
    #pragma unroll
    for (int j = 0; j < 4; ++j)
      #pragma unroll
      for (int r = 0; r < 4; ++r) {
        int row = wr * 64 + i * 16 + rb + r;
        int col = by * 128 + wc * 64 + j * 16 + cl;
        part[(size_t)kspl * 65536 + row * 512 + col] = acc[i][j][r];
      }
}

// K-split reduce + f7m add -> out[:, :512]
__global__ __launch_bounds__(512)
void k_red(const float* __restrict__ part, const float* __restrict__ f7m,
           float* __restrict__ out)
{
  int idx = blockIdx.x * 512 + threadIdx.x;   // 65536
  float s = part[idx] + part[65536 + idx] + part[131072 + idx] + part[196608 + idx];
  int row = idx >> 9, col = idx & 511;
  out[row * 1024 + col] = s + f7m[idx];
}

// P1+P2 merged: cast w_reduce (blocks 0..1151) and transpose 3x3 weights
// (blocks 1152..6271).
__global__ void k_wprep(const float* __restrict__ wred, const float* __restrict__ s0,
                        const float* __restrict__ s1, const float* __restrict__ s2,
                        const float* __restrict__ s3, const float* __restrict__ s4,
                        bf16* __restrict__ wrb, bf16* __restrict__ wt,
                        bf16* __restrict__ w1r)
{
  if (blockIdx.x < 1152) {
    int idx = (blockIdx.x * 256 + threadIdx.x) * 4;
    float4 v = *(const float4*)(wred + idx);
    bf16* d = wrb + idx;
    d[0] = (bf16)v.x; d[1] = (bf16)v.y; d[2] = (bf16)v.z; d[3] = (bf16)v.w;
    return;
  }
  int bid = blockIdx.x - 1152;
  int by = bid >> 10, bx = bid & 1023;
  const float* src;
  switch (by) {
    case 0: src = s0; break; case 1: src = s1; break; case 2: src = s2; break;
    case 3: src = s3; break; default: src = s4; break;
  }
  int q = bx * 256 + threadIdx.x;          // co*512+ci
  const float* sp = src + (size_t)q * 9;
  float tmp[9];
  #pragma unroll
  for (int e = 0; e < 9; ++e) tmp[e] = sp[e];
  if (by < 4) {
    bf16* dst = wt + (size_t)by * 2359296;
    #pragma unroll
    for (int e = 0; e < 9; ++e) dst[(size_t)e * 262144 + q] = (bf16)tmp[e];
  } else {
    int co = q >> 9, ci = q & 511;
    #pragma unroll
    for (int e = 0; e < 9; ++e) w1r[(size_t)(co * 9 + e) * 512 + ci] = (bf16)tmp[e];
  }
}

// K3: maxpool 3x3 s2 p1, 14x14 -> 7x7, bf16, 2 channels/thread
__global__ void k_pool(const bf16* __restrict__ f14, bf16* __restrict__ f7b)
{
  int idx = blockIdx.x * 256 + threadIdx.x;
  int c2 = idx & 255;
  int pp = idx >> 8;
  int n = pp / 49, p7 = pp - n * 49;
  int y = p7 / 7, x = p7 - 7 * (p7 / 7);
  int y0 = 2 * y - 1, x0 = 2 * x - 1;
  const unsigned* f14u = (const unsigned*)f14;
  float m0 = -3.4e38f, m1 = -3.4e38f;
  #pragma unroll
  for (int dy = 0; dy < 3; ++dy) {
    int iy = y0 + dy; if ((unsigned)iy >= 14u) continue;
    #pragma unroll
    for (int dx = 0; dx < 3; ++dx) {
      int ix = x0 + dx; if ((unsigned)ix >= 14u) continue;
      unsigned vv = f14u[(size_t)(n * 196 + iy * 14 + ix) * 256 + c2];
      m0 = fmaxf(m0, __builtin_bit_cast(float, vv << 16));
      m1 = fmaxf(m1, __builtin_bit_cast(float, vv & 0xffff0000u));
    }
  }
  bf16 b0 = (bf16)m0, b1 = (bf16)m1;
  unsigned pk = (unsigned)__builtin_bit_cast(unsigned short, b0)
              | ((unsigned)__builtin_bit_cast(unsigned short, b1) << 16);
  ((unsigned*)f7b)[idx] = pk;
}

// K5: group attention (8x8 within group, mask from rois)
__global__ __launch_bounds__(256)
void k_attn(const bf16* __restrict__ q, const bf16* __restrict__ k,
            const bf16* __restrict__ v, const float* __restrict__ rois,
            float* __restrict__ virt)
{
  const int p = blockIdx.x, g = blockIdx.y, t = threadIdx.x;
  __shared__ float sS[8][9];
  __shared__ float sP[8][9];
  __shared__ __attribute__((aligned(16))) bf16 sV[8][512];
  {
    int u = t;
    #pragma unroll
    for (int rep = 0; rep < 2; ++rep, u += 256) {
      int j = u >> 6, ch = u & 63;
      *(v8bf*)&sV[j][ch * 8] = *(const v8bf*)(v + ((size_t)(g * 8 + j) * 49 + p) * 512 + ch * 8);
    }
  }
  int pi = t >> 2, ls = t & 3;
  int i = pi >> 3, j = pi & 7;
  const bf16* qi = q + ((size_t)(g * 8 + i) * 49 + p) * 512;
  const bf16* kj = k + ((size_t)(g * 8 + j) * 49 + p) * 512;
  float s = 0.f;
  for (int ch = ls * 16; ch < ls * 16 + 16; ++ch) {
    v8bf a = *(const v8bf*)(qi + ch * 8);
    v8bf b = *(const v8bf*)(kj + ch * 8);
    #pragma unroll
    for (int e = 0; e < 8; ++e) s += (float)a[e] * (float)b[e];
  }
  s += __shfl_xor(s, 1);
  s += __shfl_xor(s, 2);
  if (ls == 0) sS[i][j] = s * 0.04419417382415922f;
  __syncthreads();
  if (t < 8) {
    float gi = rois[(g * 8 + t) * 5];
    float pv[8]; float mx = -3.4e38f;
    #pragma unroll
    for (int jj = 0; jj < 8; ++jj) {
      float gj = rois[(g * 8 + jj) * 5];
      float sv = (gi == gj) ? sS[t][jj] : -1e30f;
      pv[jj] = sv; mx = fmaxf(mx, sv);
    }
    float sum = 0.f;
    #pragma unroll
    for (int jj = 0; jj < 8; ++jj) { float e = expf(pv[jj] - mx); pv[jj] = e; sum += e; }
    float inv = 1.f / sum;
    #pragma unroll
    for (int jj = 0; jj < 8; ++jj) sP[t][jj] = pv[jj] * inv;
  }
  __syncthreads();
  int i2 = t >> 5, c0 = (t & 31) * 16;
  float o[16];
  #pragma unroll
  for (int e = 0; e < 16; ++e) o[e] = 0.f;
  #pragma unroll
  for (int jj = 0; jj < 8; ++jj) {
    float ww = sP[i2][jj];
    v8bf v0 = *(const v8bf*)&sV[jj][c0];
    v8bf v1 = *(const v8bf*)&sV[jj][c0 + 8];
    #pragma unroll
    for (int e = 0; e < 8; ++e) { o[e] += ww * (float)v0[e]; o[8 + e] += ww * (float)v1[e]; }
  }
  float* dst = virt + ((size_t)(g * 8 + i2) * 49 + p) * 512 + c0;
  #pragma unroll
  for (int e = 0; e < 16; ++e) dst[e] = o[e];
}

// K6: fused LN(stats+apply)+windowed-sums (blocks 0..127) and fc (128..255).
__global__ __launch_bounds__(512)
void k_ln_fc(const float* __restrict__ virt, const float* __restrict__ gamma,
             const float* __restrict__ beta, const bf16* __restrict__ f7b,
             bf16* __restrict__ A_s, float* __restrict__ f7m,
             const float* __restrict__ obm, const float* __restrict__ wfc,
             float* __restrict__ out)
{
  const int t = threadIdx.x;
  if (blockIdx.x >= 128) {
    __shared__ float sO[1024];
    int n = blockIdx.x - 128;
    for (int u = t; u < 1024; u += 512) sO[u] = obm[n * 1024 + u];
    __syncthreads();
    const float4* wp = (const float4*)(wfc + (size_t)t * 1024);
    float s = 0.f;
    for (int c4 = 0; c4 < 256; ++c4) {
      float4 w = wp[c4];
      s += w.x * sO[c4 * 4] + w.y * sO[c4 * 4 + 1] + w.z * sO[c4 * 4 + 2] + w.w * sO[c4 * 4 + 3];
    }
    out[n * 1024 + 512 + t] = fmaxf(s, 0.f);
    return;
  }
  const int n = blockIdx.x;
  const float* p = virt + (size_t)n * 25088 + t;
  float xv[49];
  float s1 = 0.f, s2 = 0.f;
  #pragma unroll
  for (int pp = 0; pp < 49; ++pp) {
    float x = p[pp * 512];
    xv[pp] = x; s1 += x; s2 += x * x;
  }
  __shared__ float r1[512], r2[512];
  r1[t] = s1; r2[t] = s2; __syncthreads();
  for (int off = 256; off; off >>= 1) {
    if (t < off) { r1[t] += r1[t + off]; r2[t] += r2[t + off]; }
    __syncthreads();
  }
  float mu = r1[0] * (1.f / 25088.f);
  float var = r2[0] * (1.f / 25088.f) - mu * mu;
  float rstd = rsqrtf(var + 1e-5f);
  float g = gamma[t], be = beta[t];
  const bf16* fp = f7b + (size_t)n * 25088 + t;
  float T = 0, R0 = 0, R6 = 0, C0 = 0, C6 = 0;
  float X00 = 0, X06 = 0, X60 = 0, X66 = 0, F = 0;
  #pragma unroll
  for (int pp = 0; pp < 49; ++pp) {
    const int u = pp / 7, v = pp - 7 * (pp / 7);
    float y = fmaxf((xv[pp] - mu) * rstd * g + be, 0.f);
    T += y;
    if (u == 0) R0 += y;
    if (u == 6) R6 += y;
    if (v == 0) C0 += y;
    if (v == 6) C6 += y;
    if (pp == 0)  X00 = y;
    if (pp == 6)  X06 = y;
    if (pp == 42) X60 = y;
    if (pp == 48) X66 = y;
    F += (float)fp[pp * 512];
  }
  float sv[9] = { T-R6-C6+X66, T-R6, T-R6-C0+X60,
                  T-C6,        T,    T-C0,
                  T-R0-C6+X06, T-R0, T-R0-C0+X00 };
  bf16* Ap = A_s + (size_t)n * 4608 + t;
  #pragma unroll
  for (int tap = 0; tap < 9; ++tap)
    Ap[tap * 512] = (bf16)(sv[tap] * (1.f / 49.f));
  f7m[n * 512 + t] = F * (1.f / 49.f);
}

// ---------------------------------------------------------------------------
extern "C" void kernel_launch(void* const* d_in, const int* in_sizes, int n_in,
                              void* d_out, int out_size, void* d_ws, size_t ws_size,
                              hipStream_t stream) {
  const float* rois     = (const float*)d_in[0];
  const float* interact = (const float*)d_in[1];
  const float* bbox     = (const float*)d_in[2];
  const float* w_reduce = (const float*)d_in[3];
  const float* w_rsize  = (const float*)d_in[4];
  const float* wq       = (const float*)d_in[5];
  const float* wk       = (const float*)d_in[6];
  const float* wv       = (const float*)d_in[7];
  const float* w1       = (const float*)d_in[8];
  const float* gamma    = (const float*)d_in[9];
  const float* beta     = (const float*)d_in[10];
  const float* wfc      = (const float*)d_in[11];
  float* out = (float*)d_out;
  char* ws = (char*)d_ws;

  size_t o = 0;
  auto take = [&](size_t sz) { size_t r = o; o += (sz + 255) & ~(size_t)255; return r; };
  bf16*  wrb   = (bf16*)(ws + take(2359296));
  bf16*  wt    = (bf16*)(ws + take(18874368));   // [4][9][512][512] bf16 (rsize,q,k,v)
  bf16*  w1r   = (bf16*)(ws + take(4718592));    // [512 co][9 tap][512 ci] bf16
  char*  Rf1   = ws + take(33554432);            // f1 (33.6MB) -> later q,k,v (19.3MB)
  bf16*  f7b   = (bf16*)(ws + take(6422528));
  float* virt  = (float*)(ws + take(12845056));
  bf16*  A_s   = (bf16*)(ws + take(1179648));
  float* f7m   = (float*)(ws + take(262144));
  float* part  = (float*)(ws + take(1048576));   // [4 ks][128][512] f32
  float* obm   = (float*)(ws + take(524288));
  bf16*  zp    = (bf16*)(ws + take(256));
  size_t fixedEnd = o;
  bf16* f14 = (bf16*)(ws + fixedEnd);            // 25.7 MB transient

  bf16* f1 = (bf16*)Rf1;
  bf16* qb = (bf16*)Rf1;
  bf16* kb = qb + 3211264;
  bf16* vb = kb + 3211264;

  hipMemsetAsync(zp, 0, 256, stream);

  // weight prep (merged cast + transpose)
  k_wprep<<<6272, 256, 0, stream>>>(w_reduce, w_rsize, wq, wk, wv, w1, wrb, wt, w1r);

  // fused transpose+reduce GEMM (reads interact directly)
  k_gemm_reduce_f<<<512, 256, 0, stream>>>(interact, wrb, f1);

  k_conv_rsize<<<392, 256, 0, stream>>>(f1, wt, f14);
  k_pool<<<6272, 256, 0, stream>>>(f14, f7b);

  // fused qkv convs (blocks 0-299) + obm (300-2347)
  k_conv_qkv<<<2348, 256, 0, stream>>>(f7b, wt + (size_t)1 * 2359296, qb, zp, bbox, obm);

  k_attn<<<dim3(49, 16), 256, 0, stream>>>(qb, kb, vb, rois, virt);

  k_ln_fc<<<256, 512, 0, stream>>>(virt, gamma, beta, f7b, A_s, f7m, obm, wfc, out);

  k_gemm_s<<<dim3(4, 4), 256, 0, stream>>>(A_s, w1r, part);
  k_red<<<128, 512, 0, stream>>>(part, f7m, out);
}

// Round 9
// 541.963 us; speedup vs baseline: 1.6896x; 1.6896x over previous
//
#include <hip/hip_runtime.h>
#include <hip/hip_bf16.h>
#include <math.h>

typedef __bf16 bf16;
typedef __bf16 v8bf __attribute__((ext_vector_type(8)));
typedef float f32x4 __attribute__((ext_vector_type(4)));

// async global->LDS, 16B per lane (per-thread LDS offset is t*16, lane-linear).
#define GLDS16(g, l) __builtin_amdgcn_global_load_lds( \
    (const __attribute__((address_space(1))) void*)(g), \
    (__attribute__((address_space(3))) void*)(l), 16, 0, 0)

// bijective XCD-chunk swizzle (m204 variant, works for any nwg)
__device__ __forceinline__ int xcd_swz(int bid, int nwg) {
  int xcd = bid & 7, off = bid >> 3;
  int q = nwg >> 3, r = nwg & 7;
  return (xcd < r ? xcd * (q + 1) : r * (q + 1) + (xcd - r) * q) + off;
}

// ===========================================================================
// 256x128 MFMA core, BK=32, ring-3 LDS (3 x 24KB = 72KB -> 2 blocks/CU),
// 256 thr = 4 waves (2M x 2N), per-wave output 128x64 (8x4 fragments):
// 32 MFMA per 12 ds_read_b128 (B-frags reused across both M-halves).
// Slot: A 16KB = [128 lds-rows][128B], lds-row r packs global A-rows (r, r+128)
// (64B of k each); B 8KB = [64 rows][128B] packing B-rows (r, r+64).
// XOR swizzle: phys col = logical ^ ((row&7)<<4).
// Staging (linear gload_lds): thread t, issue i -> lds-row i*32+(t>>3), phys
// col (t&7)*16; logical lb = ((t&7)<<4)^(((t>>3)&7)<<4); hi=lb>>6 picks the
// packed row half (+128 A / +64 B), kb=lb&63 the k-byte. 6 gloads per group
// (4 A + 2 B). Pipeline: compute g from s0, stage g+2 into s2 (slot of g-1,
// reads done before end-of-(g-1) barrier), vmcnt(12) = stages g+1,g+2 in
// flight; tail 6 -> 0. Barrier after vmcnt makes all waves' stage(g) visible.
// MFMA C/D: col=lane&15, row=4*(lane>>4)+reg.
// ===========================================================================
#define RING_COMPUTE() do { \
  v8bf b_[4], a_[4]; \
  _Pragma("unroll") for (int _j = 0; _j < 4; ++_j) { \
    int _lr = _j * 16 + l15; \
    int _c = (wn * 64 + colb) ^ ((_lr & 7) << 4); \
    b_[_j] = *(const v8bf*)(s0 + 16384 + _lr * 128 + _c); } \
  _Pragma("unroll") for (int _i = 0; _i < 4; ++_i) { \
    int _lr = _i * 16 + l15; \
    int _c = (wm * 64 + colb) ^ ((_lr & 7) << 4); \
    a_[_i] = *(const v8bf*)(s0 + _lr * 128 + _c); } \
  __builtin_amdgcn_s_setprio(1); \
  _Pragma("unroll") for (int _i = 0; _i < 4; ++_i) \
  _Pragma("unroll") for (int _j = 0; _j < 4; ++_j) \
    acc[_i][_j] = __builtin_amdgcn_mfma_f32_16x16x32_bf16(a_[_i], b_[_j], acc[_i][_j], 0, 0, 0); \
  __builtin_amdgcn_s_setprio(0); \
  _Pragma("unroll") for (int _i = 0; _i < 4; ++_i) { \
    int _lr = (_i + 4) * 16 + l15; \
    int _c = (wm * 64 + colb) ^ ((_lr & 7) << 4); \
    a_[_i] = *(const v8bf*)(s0 + _lr * 128 + _c); } \
  __builtin_amdgcn_s_setprio(1); \
  _Pragma("unroll") for (int _i = 0; _i < 4; ++_i) \
  _Pragma("unroll") for (int _j = 0; _j < 4; ++_j) \
    acc[_i + 4][_j] = __builtin_amdgcn_mfma_f32_16x16x32_bf16(a_[_i], b_[_j], acc[_i + 4][_j], 0, 0, 0); \
  __builtin_amdgcn_s_setprio(0); \
} while (0)

#define RING_LOOP(NG, STAGE) do { \
  STAGE(0, s0); STAGE(1, s1); \
  for (int g = 0; g < (NG); ++g) { \
    if (g + 2 < (NG)) { STAGE(g + 2, s2); } \
    if (g + 2 < (NG))       asm volatile("s_waitcnt vmcnt(12)" ::: "memory"); \
    else if (g + 2 == (NG)) asm volatile("s_waitcnt vmcnt(6)" ::: "memory"); \
    else                    asm volatile("s_waitcnt vmcnt(0)" ::: "memory"); \
    __builtin_amdgcn_s_barrier(); \
    __builtin_amdgcn_sched_barrier(0); \
    RING_COMPUTE(); \
    __builtin_amdgcn_sched_barrier(0); \
    __builtin_amdgcn_s_barrier(); \
    char* _tmp = s0; s0 = s1; s1 = s2; s2 = _tmp; \
  } \
} while (0)

// ---------------------------------------------------------------------------
// G1: 1x1 reduce conv + ReLU. A = interact^T bf16 [m][2304], B = wrb [512][2304].
// Grid: (M/256) x 4, by fast for A-tile L2 reuse. Groups: 2304/32 = 72.
// ---------------------------------------------------------------------------
__global__ __launch_bounds__(256, 2)
void k_gemm_reduce(const bf16* __restrict__ A, const bf16* __restrict__ B,
                   bf16* __restrict__ f1, int mbase)
{
  __shared__ __attribute__((aligned(16))) char lds[73728];
  char *s0 = lds, *s1 = lds + 24576, *s2 = lds + 49152;
  const int s = xcd_swz(blockIdx.x, gridDim.x);
  const int by = s & 3, bx = s >> 2;
  const int t = threadIdx.x, lane = t & 63, w = t >> 6;
  const int wm = w >> 1, wn = w & 1;
  const int l15 = lane & 15, colb = (lane >> 4) << 4;
  const int tr = t >> 3;
  const int lb = ((t & 7) << 4) ^ ((tr & 7) << 4);
  const int hi = lb >> 6, kb = lb & 63;
  const int t16 = t * 16;
  const char* pa[4]; const char* pb[2];
  #pragma unroll
  for (int i = 0; i < 4; ++i)
    pa[i] = (const char*)A + (size_t)(bx * 256 + i * 32 + tr + hi * 128) * 4608 + kb;
  #pragma unroll
  for (int i = 0; i < 2; ++i)
    pb[i] = (const char*)B + (size_t)(by * 128 + i * 32 + tr + hi * 64) * 4608 + kb;
  #define SG(kt, ring) do { \
    _Pragma("unroll") for (int _i = 0; _i < 4; ++_i) \
      GLDS16(pa[_i] + (size_t)(kt) * 64, (ring) + _i * 4096 + t16); \
    _Pragma("unroll") for (int _i = 0; _i < 2; ++_i) \
      GLDS16(pb[_i] + (size_t)(kt) * 64, (ring) + 16384 + _i * 4096 + t16); } while (0)
  f32x4 acc[8][4] = {};
  RING_LOOP(72, SG);
  const int rbase = (lane >> 4) << 2, cl = lane & 15;
  #pragma unroll
  for (int i = 0; i < 8; ++i)
    #pragma unroll
    for (int j = 0; j < 4; ++j)
      #pragma unroll
      for (int r = 0; r < 4; ++r) {
        int row = mbase + bx * 256 + wm * 128 + i * 16 + rbase + r;
        int col = by * 128 + wn * 64 + j * 16 + cl;
        f1[(size_t)row * 512 + col] = (bf16)fmaxf(acc[i][j][r], 0.f);
      }
}

// ---------------------------------------------------------------------------
// G2: 3x3 VALID conv (16x16 -> 14x14). f1 NHWC bf16 -> f14 NHWC bf16.
// M=25088 (98 bx) x 4 by = 392 blocks. Groups: 144 (9 taps x 16).
// ---------------------------------------------------------------------------
__global__ __launch_bounds__(256, 2)
void k_conv_rsize(const bf16* __restrict__ f1, const bf16* __restrict__ wt,
                  bf16* __restrict__ f14)
{
  __shared__ __attribute__((aligned(16))) char lds[73728];
  char *s0 = lds, *s1 = lds + 24576, *s2 = lds + 49152;
  const int s = xcd_swz(blockIdx.x, gridDim.x);
  const int by = s & 3, bx = s >> 2;
  const int t = threadIdx.x, lane = t & 63, w = t >> 6;
  const int wm = w >> 1, wn = w & 1;
  const int l15 = lane & 15, colb = (lane >> 4) << 4;
  const int tr = t >> 3;
  const int lb = ((t & 7) << 4) ^ ((tr & 7) << 4);
  const int hi = lb >> 6, kb = lb & 63;
  const int t16 = t * 16;
  int abase[4]; const char* pb[2];
  #pragma unroll
  for (int i = 0; i < 4; ++i) {
    int m = bx * 256 + i * 32 + tr + hi * 128;
    int n = m / 196, rem = m - n * 196;
    int y = rem / 14, x = rem - 14 * (rem / 14);
    abase[i] = n * 256 + y * 16 + x;
  }
  #pragma unroll
  for (int i = 0; i < 2; ++i)
    pb[i] = (const char*)wt + (size_t)(by * 128 + i * 32 + tr + hi * 64) * 1024 + kb;
  const char* f1c = (const char*)f1 + kb;
  #define SC(kt, ring) do { int _tap = (kt) >> 4, _ko = ((kt) & 15) << 6; \
    int _dy = (_tap * 11) >> 5, _dx = _tap - _dy * 3; \
    int _df = (_dy * 16 + _dx) << 10; \
    _Pragma("unroll") for (int _i = 0; _i < 4; ++_i) \
      GLDS16(f1c + ((size_t)abase[_i] << 10) + _df + _ko, (ring) + _i * 4096 + t16); \
    _Pragma("unroll") for (int _i = 0; _i < 2; ++_i) \
      GLDS16(pb[_i] + (size_t)_tap * 524288 + _ko, (ring) + 16384 + _i * 4096 + t16); } while (0)
  f32x4 acc[8][4] = {};
  RING_LOOP(144, SC);
  const int rbase = (lane >> 4) << 2, cl = lane & 15;
  #pragma unroll
  for (int i = 0; i < 8; ++i)
    #pragma unroll
    for (int j = 0; j < 4; ++j)
      #pragma unroll
      for (int r = 0; r < 4; ++r) {
        int row = bx * 256 + wm * 128 + i * 16 + rbase + r;
        int col = by * 128 + wn * 64 + j * 16 + cl;
        f14[(size_t)row * 512 + col] = (bf16)acc[i][j][r];
      }
}

// ---------------------------------------------------------------------------
// G4: fused q/k/v 3x3 SAME conv on 7x7. M=6272 (25 bx, masked tail) x
// 12 (tensor x by) = 300 conv blocks; blocks 300..2347 = obm mean (overlaps
// bbox HBM reads with qkv compute). Groups: 144.
// ---------------------------------------------------------------------------
__global__ __launch_bounds__(256, 2)
void k_conv_qkv(const bf16* __restrict__ fin, const bf16* __restrict__ wt,
                bf16* __restrict__ qkv, const bf16* __restrict__ zp,
                const float* __restrict__ bbox, float* __restrict__ obm)
{
  __shared__ __attribute__((aligned(16))) char lds[73728];
  char *s0 = lds, *s1 = lds + 24576, *s2 = lds + 49152;
  const int t = threadIdx.x;
  if (blockIdx.x >= 300) {
    int bid = blockIdx.x - 300;           // 2048 blocks: 128 n x 16 cgroups
    int n = bid >> 4;
    int c = (bid & 15) * 64 + (t >> 2);
    int seg = t & 3;
    const float4* p4 = (const float4*)(bbox + ((size_t)n * 1024 + c) * 196);
    float sum = 0.f;
    for (int k = seg; k < 49; k += 4) { float4 ww = p4[k]; sum += ww.x + ww.y + ww.z + ww.w; }
    sum += __shfl_xor(sum, 1);
    sum += __shfl_xor(sum, 2);
    if (seg == 0) obm[n * 1024 + c] = sum * (1.f / 196.f);
    return;
  }
  const int s = xcd_swz(blockIdx.x, 300);
  const int q12 = s % 12, bx = s / 12;
  const int tensor = q12 >> 2, byl = q12 & 3;
  const char* wtc = (const char*)wt + (size_t)tensor * 4718592;
  bf16* outp = qkv + (size_t)tensor * 3211264;
  const int lane = t & 63, w = t >> 6;
  const int wm = w >> 1, wn = w & 1;
  const int l15 = lane & 15, colb = (lane >> 4) << 4;
  const int tr = t >> 3;
  const int lb = ((t & 7) << 4) ^ ((tr & 7) << 4);
  const int hi = lb >> 6, kb = lb & 63;
  const int t16 = t * 16;
  int nb[4], py[4], px[4]; const char* pb[2];
  #pragma unroll
  for (int i = 0; i < 4; ++i) {
    int m = bx * 256 + i * 32 + tr + hi * 128;
    if (m > 6271) m = 6271;
    int n = m / 49, rem = m - n * 49;
    nb[i] = n * 49;
    py[i] = rem / 7 - 1;
    px[i] = rem - 7 * (rem / 7) - 1;
  }
  #pragma unroll
  for (int i = 0; i < 2; ++i)
    pb[i] = wtc + (size_t)(byl * 128 + i * 32 + tr + hi * 64) * 1024 + kb;
  const char* finc = (const char*)fin + kb;
  const char* zpc = (const char*)zp;
  #define SQ(kt, ring) do { int _tap = (kt) >> 4, _ko = ((kt) & 15) << 6; \
    int _dy = (_tap * 11) >> 5, _dx = _tap - _dy * 3; \
    _Pragma("unroll") for (int _i = 0; _i < 4; ++_i) { \
      int _iy = py[_i] + _dy, _ix = px[_i] + _dx; \
      const char* _sp = ((unsigned)_iy < 7u && (unsigned)_ix < 7u) \
          ? finc + (size_t)(nb[_i] + _iy * 7 + _ix) * 1024 + _ko : zpc; \
      GLDS16(_sp, (ring) + _i * 4096 + t16); } \
    _Pragma("unroll") for (int _i = 0; _i < 2; ++_i) \
      GLDS16(pb[_i] + (size_t)_tap * 524288 + _ko, (ring) + 16384 + _i * 4096 + t16); } while (0)
  f32x4 acc[8][4] = {};
  RING_LOOP(144, SQ);
  const int rbase = (lane >> 4) << 2, cl = lane & 15;
  #pragma unroll
  for (int i = 0; i < 8; ++i)
    #pragma unroll
    for (int j = 0; j < 4; ++j)
      #pragma unroll
      for (int r = 0; r < 4; ++r) {
        int row = bx * 256 + wm * 128 + i * 16 + rbase + r;
        if (row < 6272) {
          int col = byl * 128 + wn * 64 + j * 16 + cl;
          outp[(size_t)row * 512 + col] = (bf16)acc[i][j][r];
        }
      }
}

// ===========================================================================
// Old 128x128 core (kept for the tiny gemm_s)
// ===========================================================================
__device__ __forceinline__ void tile_compute(const char* ldsA, const char* ldsB,
                                             f32x4 (&acc)[4][4], int wr, int wc, int lane) {
  const int l15 = lane & 15;
  const int colb = (lane >> 4) << 4;
  #pragma unroll
  for (int kk = 0; kk < 2; ++kk) {
    v8bf a[4], b[4];
    #pragma unroll
    for (int i = 0; i < 4; ++i) {
      int ra = wr * 64 + i * 16 + l15;
      int ca = ((kk << 6) | colb) ^ ((ra & 7) << 4);
      a[i] = *(const v8bf*)(ldsA + ra * 128 + ca);
    }
    #pragma unroll
    for (int j = 0; j < 4; ++j) {
      int rb = wc * 64 + j * 16 + l15;
      int cb = ((kk << 6) | colb) ^ ((rb & 7) << 4);
      b[j] = *(const v8bf*)(ldsB + rb * 128 + cb);
    }
    __builtin_amdgcn_s_setprio(1);
    #pragma unroll
    for (int i = 0; i < 4; ++i)
      #pragma unroll
      for (int j = 0; j < 4; ++j)
        acc[i][j] = __builtin_amdgcn_mfma_f32_16x16x32_bf16(a[i], b[j], acc[i][j], 0, 0, 0);
    __builtin_amdgcn_s_setprio(0);
  }
}

#define PIPELINE_LOOP(NK)                                                   \
  stage(0, lds);                                                            \
  stage(1, lds + 32768);                                                    \
  int cur = 0;                                                              \
  for (int ks = 0; ks < (NK) - 1; ++ks) {                                   \
    asm volatile("s_waitcnt vmcnt(8)" ::: "memory");                        \
    __builtin_amdgcn_s_barrier();                                           \
    __builtin_amdgcn_sched_barrier(0);                                      \
    tile_compute(lds + cur * 32768, lds + cur * 32768 + 16384, acc, wr, wc, lane); \
    __builtin_amdgcn_sched_barrier(0);                                      \
    __builtin_amdgcn_s_barrier();                                           \
    __builtin_amdgcn_sched_barrier(0);                                      \
    if (ks + 2 < (NK)) stage(ks + 2, lds + cur * 32768);                    \
    cur ^= 1;                                                               \
  }                                                                         \
  asm volatile("s_waitcnt vmcnt(0)" ::: "memory");                          \
  __builtin_amdgcn_s_barrier();                                             \
  __builtin_amdgcn_sched_barrier(0);                                        \
  tile_compute(lds + cur * 32768, lds + cur * 32768 + 16384, acc, wr, wc, lane);

// G6: w1-conv+ho-mean GEMM, K-split: part[ks] = A_s[:,ksK] @ w1r[:,ksK]^T.
__global__ __launch_bounds__(256)
void k_gemm_s(const bf16* __restrict__ A_s, const bf16* __restrict__ w1r,
              float* __restrict__ part)
{
  __shared__ __attribute__((aligned(16))) char lds[65536];
  const int by = blockIdx.x, kspl = blockIdx.y;
  const int t = threadIdx.x, lane = t & 63, w = t >> 6, wr = w >> 1, wc = w & 1;
  const int tr = t >> 3;
  const int cphys = ((t & 7) << 4) ^ ((tr & 7) << 4);
  const char* pa[4]; const char* pb[4];
  #pragma unroll
  for (int i = 0; i < 4; ++i) {
    int r = i * 32 + tr;
    pa[i] = (const char*)A_s + (size_t)r * 9216 + kspl * 2304 + cphys;
    pb[i] = (const char*)w1r + (size_t)(by * 128 + r) * 9216 + kspl * 2304 + cphys;
  }
  const int lo = t * 16;
  auto stage = [&](int ks, char* base) {
    #pragma unroll
    for (int i = 0; i < 4; ++i) GLDS16(pa[i] + ks * 128, base + lo + i * 4096);
    #pragma unroll
    for (int i = 0; i < 4; ++i) GLDS16(pb[i] + ks * 128, base + 16384 + lo + i * 4096);
  };
  f32x4 acc[4][4] = {};
  PIPELINE_LOOP(18)
  const int rb = (lane >> 4) << 2, cl = lane & 15;
  #pragma unroll
  for (int i = 0; i < 4; ++i)
    #pragma unroll
    for (int j = 0; j < 4; ++j)
      #pragma unroll
      for (int r = 0; r < 4; ++r) {
        int row = wr * 64 + i * 16 + rb + r;
        int col = by * 128 + wc * 64 + j * 16 + cl;
        part[(size_t)kspl * 65536 + row * 512 + col] = acc[i][j][r];
      }
}

// K-split reduce + f7m add -> out[:, :512]
__global__ __launch_bounds__(512)
void k_red(const float* __restrict__ part, const float* __restrict__ f7m,
           float* __restrict__ out)
{
  int idx = blockIdx.x * 512 + threadIdx.x;   // 65536
  float s = part[idx] + part[65536 + idx] + part[131072 + idx] + part[196608 + idx];
  int row = idx >> 9, col = idx & 511;
  out[row * 1024 + col] = s + f7m[idx];
}

// P0: transpose+cast interact (n,2304,256) f32 -> A1 bf16 [(nl*256+p)][2304].
// Coalesced float4 loads, 16B packed v8bf stores.
__global__ void k_tin(const float* __restrict__ in, bf16* __restrict__ A1, int n0)
{
  __shared__ float tile[64][36];
  const int k0 = blockIdx.x * 64, p0 = blockIdx.y * 32, nl = blockIdx.z;
  const int n = n0 + nl;
  const int t = threadIdx.x;
  const float* src = in + (size_t)n * 2304 * 256;
  #pragma unroll
  for (int rep = 0; rep < 2; ++rep) {
    int idx = t + rep * 256;
    int row = idx >> 3, c4 = (idx & 7) * 4;
    float4 v = *(const float4*)(src + (size_t)(k0 + row) * 256 + p0 + c4);
    tile[row][c4] = v.x; tile[row][c4 + 1] = v.y;
    tile[row][c4 + 2] = v.z; tile[row][c4 + 3] = v.w;
  }
  __syncthreads();
  const int pl = t >> 3, ke = (t & 7) * 8;
  v8bf o;
  #pragma unroll
  for (int e = 0; e < 8; ++e) o[e] = (bf16)tile[ke + e][pl];
  bf16* dst = A1 + (size_t)nl * 256 * 2304;
  *(v8bf*)(dst + (size_t)(p0 + pl) * 2304 + k0 + ke) = o;
}

// P1+P2 merged: cast w_reduce (blocks 0..1151) and transpose 3x3 weights
// (blocks 1152..6271).
__global__ void k_wprep(const float* __restrict__ wred, const float* __restrict__ s0,
                        const float* __restrict__ s1, const float* __restrict__ s2,
                        const float* __restrict__ s3, const float* __restrict__ s4,
                        bf16* __restrict__ wrb, bf16* __restrict__ wt,
                        bf16* __restrict__ w1r)
{
  if (blockIdx.x < 1152) {
    int idx = (blockIdx.x * 256 + threadIdx.x) * 4;
    float4 v = *(const float4*)(wred + idx);
    bf16* d = wrb + idx;
    d[0] = (bf16)v.x; d[1] = (bf16)v.y; d[2] = (bf16)v.z; d[3] = (bf16)v.w;
    return;
  }
  int bid = blockIdx.x - 1152;
  int by = bid >> 10, bx = bid & 1023;
  const float* src;
  switch (by) {
    case 0: src = s0; break; case 1: src = s1; break; case 2: src = s2; break;
    case 3: src = s3; break; default: src = s4; break;
  }
  int q = bx * 256 + threadIdx.x;          // co*512+ci
  const float* sp = src + (size_t)q * 9;
  float tmp[9];
  #pragma unroll
  for (int e = 0; e < 9; ++e) tmp[e] = sp[e];
  if (by < 4) {
    bf16* dst = wt + (size_t)by * 2359296;
    #pragma unroll
    for (int e = 0; e < 9; ++e) dst[(size_t)e * 262144 + q] = (bf16)tmp[e];
  } else {
    int co = q >> 9, ci = q & 511;
    #pragma unroll
    for (int e = 0; e < 9; ++e) w1r[(size_t)(co * 9 + e) * 512 + ci] = (bf16)tmp[e];
  }
}

// K3: maxpool 3x3 s2 p1, 14x14 -> 7x7, bf16, 2 channels/thread
__global__ void k_pool(const bf16* __restrict__ f14, bf16* __restrict__ f7b)
{
  int idx = blockIdx.x * 256 + threadIdx.x;
  int c2 = idx & 255;
  int pp = idx >> 8;
  int n = pp / 49, p7 = pp - n * 49;
  int y = p7 / 7, x = p7 - 7 * (p7 / 7);
  int y0 = 2 * y - 1, x0 = 2 * x - 1;
  const unsigned* f14u = (const unsigned*)f14;
  float m0 = -3.4e38f, m1 = -3.4e38f;
  #pragma unroll
  for (int dy = 0; dy < 3; ++dy) {
    int iy = y0 + dy; if ((unsigned)iy >= 14u) continue;
    #pragma unroll
    for (int dx = 0; dx < 3; ++dx) {
      int ix = x0 + dx; if ((unsigned)ix >= 14u) continue;
      unsigned vv = f14u[(size_t)(n * 196 + iy * 14 + ix) * 256 + c2];
      m0 = fmaxf(m0, __builtin_bit_cast(float, vv << 16));
      m1 = fmaxf(m1, __builtin_bit_cast(float, vv & 0xffff0000u));
    }
  }
  bf16 b0 = (bf16)m0, b1 = (bf16)m1;
  unsigned pk = (unsigned)__builtin_bit_cast(unsigned short, b0)
              | ((unsigned)__builtin_bit_cast(unsigned short, b1) << 16);
  ((unsigned*)f7b)[idx] = pk;
}

// K5: group attention (8x8 within group, mask from rois)
__global__ __launch_bounds__(256)
void k_attn(const bf16* __restrict__ q, const bf16* __restrict__ k,
            const bf16* __restrict__ v, const float* __restrict__ rois,
            float* __restrict__ virt)
{
  const int p = blockIdx.x, g = blockIdx.y, t = threadIdx.x;
  __shared__ float sS[8][9];
  __shared__ float sP[8][9];
  __shared__ __attribute__((aligned(16))) bf16 sV[8][512];
  {
    int u = t;
    #pragma unroll
    for (int rep = 0; rep < 2; ++rep, u += 256) {
      int j = u >> 6, ch = u & 63;
      *(v8bf*)&sV[j][ch * 8] = *(const v8bf*)(v + ((size_t)(g * 8 + j) * 49 + p) * 512 + ch * 8);
    }
  }
  int pi = t >> 2, ls = t & 3;
  int i = pi >> 3, j = pi & 7;
  const bf16* qi = q + ((size_t)(g * 8 + i) * 49 + p) * 512;
  const bf16* kj = k + ((size_t)(g * 8 + j) * 49 + p) * 512;
  float s = 0.f;
  for (int ch = ls * 16; ch < ls * 16 + 16; ++ch) {
    v8bf a = *(const v8bf*)(qi + ch * 8);
    v8bf b = *(const v8bf*)(kj + ch * 8);
    #pragma unroll
    for (int e = 0; e < 8; ++e) s += (float)a[e] * (float)b[e];
  }
  s += __shfl_xor(s, 1);
  s += __shfl_xor(s, 2);
  if (ls == 0) sS[i][j] = s * 0.04419417382415922f;
  __syncthreads();
  if (t < 8) {
    float gi = rois[(g * 8 + t) * 5];
    float pv[8]; float mx = -3.4e38f;
    #pragma unroll
    for (int jj = 0; jj < 8; ++jj) {
      float gj = rois[(g * 8 + jj) * 5];
      float sv = (gi == gj) ? sS[t][jj] : -1e30f;
      pv[jj] = sv; mx = fmaxf(mx, sv);
    }
    float sum = 0.f;
    #pragma unroll
    for (int jj = 0; jj < 8; ++jj) { float e = expf(pv[jj] - mx); pv[jj] = e; sum += e; }
    float inv = 1.f / sum;
    #pragma unroll
    for (int jj = 0; jj < 8; ++jj) sP[t][jj] = pv[jj] * inv;
  }
  __syncthreads();
  int i2 = t >> 5, c0 = (t & 31) * 16;
  float o[16];
  #pragma unroll
  for (int e = 0; e < 16; ++e) o[e] = 0.f;
  #pragma unroll
  for (int jj = 0; jj < 8; ++jj) {
    float ww = sP[i2][jj];
    v8bf v0 = *(const v8bf*)&sV[jj][c0];
    v8bf v1 = *(const v8bf*)&sV[jj][c0 + 8];
    #pragma unroll
    for (int e = 0; e < 8; ++e) { o[e] += ww * (float)v0[e]; o[8 + e] += ww * (float)v1[e]; }
  }
  float* dst = virt + ((size_t)(g * 8 + i2) * 49 + p) * 512 + c0;
  #pragma unroll
  for (int e = 0; e < 16; ++e) dst[e] = o[e];
}

// K6: fused LN(stats+apply)+windowed-sums (blocks 0..127) and fc (128..255).
__global__ __launch_bounds__(512)
void k_ln_fc(const float* __restrict__ virt, const float* __restrict__ gamma,
             const float* __restrict__ beta, const bf16* __restrict__ f7b,
             bf16* __restrict__ A_s, float* __restrict__ f7m,
             const float* __restrict__ obm, const float* __restrict__ wfc,
             float* __restrict__ out)
{
  const int t = threadIdx.x;
  if (blockIdx.x >= 128) {
    __shared__ float sO[1024];
    int n = blockIdx.x - 128;
    for (int u = t; u < 1024; u += 512) sO[u] = obm[n * 1024 + u];
    __syncthreads();
    const float4* wp = (const float4*)(wfc + (size_t)t * 1024);
    float s = 0.f;
    for (int c4 = 0; c4 < 256; ++c4) {
      float4 w = wp[c4];
      s += w.x * sO[c4 * 4] + w.y * sO[c4 * 4 + 1] + w.z * sO[c4 * 4 + 2] + w.w * sO[c4 * 4 + 3];
    }
    out[n * 1024 + 512 + t] = fmaxf(s, 0.f);
    return;
  }
  const int n = blockIdx.x;
  const float* p = virt + (size_t)n * 25088 + t;
  float xv[49];
  float s1 = 0.f, s2 = 0.f;
  #pragma unroll
  for (int pp = 0; pp < 49; ++pp) {
    float x = p[pp * 512];
    xv[pp] = x; s1 += x; s2 += x * x;
  }
  __shared__ float r1[512], r2[512];
  r1[t] = s1; r2[t] = s2; __syncthreads();
  for (int off = 256; off; off >>= 1) {
    if (t < off) { r1[t] += r1[t + off]; r2[t] += r2[t + off]; }
    __syncthreads();
  }
  float mu = r1[0] * (1.f / 25088.f);
  float var = r2[0] * (1.f / 25088.f) - mu * mu;
  float rstd = rsqrtf(var + 1e-5f);
  float g = gamma[t], be = beta[t];
  const bf16* fp = f7b + (size_t)n * 25088 + t;
  float T = 0, R0 = 0, R6 = 0, C0 = 0, C6 = 0;
  float X00 = 0, X06 = 0, X60 = 0, X66 = 0, F = 0;
  #pragma unroll
  for (int pp = 0; pp < 49; ++pp) {
    const int u = pp / 7, v = pp - 7 * (pp / 7);
    float y = fmaxf((xv[pp] - mu) * rstd * g + be, 0.f);
    T += y;
    if (u == 0) R0 += y;
    if (u == 6) R6 += y;
    if (v == 0) C0 += y;
    if (v == 6) C6 += y;
    if (pp == 0)  X00 = y;
    if (pp == 6)  X06 = y;
    if (pp == 42) X60 = y;
    if (pp == 48) X66 = y;
    F += (float)fp[pp * 512];
  }
  float sv[9] = { T-R6-C6+X66, T-R6, T-R6-C0+X60,
                  T-C6,        T,    T-C0,
                  T-R0-C6+X06, T-R0, T-R0-C0+X00 };
  bf16* Ap = A_s + (size_t)n * 4608 + t;
  #pragma unroll
  for (int tap = 0; tap < 9; ++tap)
    Ap[tap * 512] = (bf16)(sv[tap] * (1.f / 49.f));
  f7m[n * 512 + t] = F * (1.f / 49.f);
}

// ---------------------------------------------------------------------------
extern "C" void kernel_launch(void* const* d_in, const int* in_sizes, int n_in,
                              void* d_out, int out_size, void* d_ws, size_t ws_size,
                              hipStream_t stream) {
  const float* rois     = (const float*)d_in[0];
  const float* interact = (const float*)d_in[1];
  const float* bbox     = (const float*)d_in[2];
  const float* w_reduce = (const float*)d_in[3];
  const float* w_rsize  = (const float*)d_in[4];
  const float* wq       = (const float*)d_in[5];
  const float* wk       = (const float*)d_in[6];
  const float* wv       = (const float*)d_in[7];
  const float* w1       = (const float*)d_in[8];
  const float* gamma    = (const float*)d_in[9];
  const float* beta     = (const float*)d_in[10];
  const float* wfc      = (const float*)d_in[11];
  float* out = (float*)d_out;
  char* ws = (char*)d_ws;

  size_t o = 0;
  auto take = [&](size_t sz) { size_t r = o; o += (sz + 255) & ~(size_t)255; return r; };
  bf16*  wrb   = (bf16*)(ws + take(2359296));
  bf16*  wt    = (bf16*)(ws + take(18874368));   // [4][9][512][512] bf16 (rsize,q,k,v)
  bf16*  w1r   = (bf16*)(ws + take(4718592));    // [512 co][9 tap][512 ci] bf16
  char*  Rf1   = ws + take(33554432);            // f1 (33.6MB) -> later q,k,v (19.3MB)
  bf16*  f7b   = (bf16*)(ws + take(6422528));
  float* virt  = (float*)(ws + take(12845056));
  bf16*  A_s   = (bf16*)(ws + take(1179648));
  float* f7m   = (float*)(ws + take(262144));
  float* part  = (float*)(ws + take(1048576));   // [4 ks][128][512] f32
  float* obm   = (float*)(ws + take(524288));
  bf16*  zp    = (bf16*)(ws + take(256));
  size_t fixedEnd = o;
  const size_t A1_FULL = 150994944;
  bool full = (ws_size >= fixedEnd + A1_FULL);
  bf16* A1  = (bf16*)(ws + fixedEnd);
  bf16* f14 = (bf16*)(ws + fixedEnd);            // aliases A1 after reduce GEMM

  bf16* f1 = (bf16*)Rf1;
  bf16* qb = (bf16*)Rf1;
  bf16* kb = qb + 3211264;
  bf16* vb = kb + 3211264;

  hipMemsetAsync(zp, 0, 256, stream);

  // weight prep (merged cast + transpose)
  k_wprep<<<6272, 256, 0, stream>>>(w_reduce, w_rsize, wq, wk, wv, w1, wrb, wt, w1r);

  if (full) {
    k_tin<<<dim3(36, 8, 128), 256, 0, stream>>>(interact, A1, 0);
    k_gemm_reduce<<<512, 256, 0, stream>>>(A1, wrb, f1, 0);
  } else {
    for (int ch = 0; ch < 4; ++ch) {
      k_tin<<<dim3(36, 8, 32), 256, 0, stream>>>(interact, A1, ch * 32);
      k_gemm_reduce<<<128, 256, 0, stream>>>(A1, wrb, f1, ch * 8192);
    }
  }

  k_conv_rsize<<<392, 256, 0, stream>>>(f1, wt, f14);
  k_pool<<<6272, 256, 0, stream>>>(f14, f7b);

  // fused qkv convs (blocks 0-299) + obm (300-2347)
  k_conv_qkv<<<2348, 256, 0, stream>>>(f7b, wt + (size_t)1 * 2359296, qb, zp, bbox, obm);

  k_attn<<<dim3(49, 16), 256, 0, stream>>>(qb, kb, vb, rois, virt);

  k_ln_fc<<<256, 512, 0, stream>>>(virt, gamma, beta, f7b, A_s, f7m, obm, wfc, out);

  k_gemm_s<<<dim3(4, 4), 256, 0, stream>>>(A_s, w1r, part);
  k_red<<<128, 512, 0, stream>>>(part, f7m, out);
}

// Round 10
// 516.289 us; speedup vs baseline: 1.7736x; 1.0497x over previous
//
#include <hip/hip_runtime.h>
#include <hip/hip_bf16.h>
#include <math.h>

typedef __bf16 bf16;
typedef __bf16 v8bf __attribute__((ext_vector_type(8)));
typedef float f32x4 __attribute__((ext_vector_type(4)));

// async global->LDS, 16B per lane (per-thread LDS offset is t*16, lane-linear).
#define GLDS16(g, l) __builtin_amdgcn_global_load_lds( \
    (const __attribute__((address_space(1))) void*)(g), \
    (__attribute__((address_space(3))) void*)(l), 16, 0, 0)

// bijective XCD-chunk swizzle (m204 variant, works for any nwg)
__device__ __forceinline__ int xcd_swz(int bid, int nwg) {
  int xcd = bid & 7, off = bid >> 3;
  int q = nwg >> 3, r = nwg & 7;
  return (xcd < r ? xcd * (q + 1) : r * (q + 1) + (xcd - r) * q) + off;
}

#define SBZ __builtin_amdgcn_sched_barrier(0)
#define BARR __builtin_amdgcn_s_barrier()

// ===========================================================================
// 8-phase 256x256 core (m201-style). 512 thr = 8 waves (2M x 4N), per-wave
// output 128x64. BK=64 per K-tile. LDS (dynamic, 128KB) = 2 dbuf x
// {A-half0, A-half1, B-half0, B-half1} x 16KB. Half-tile = 128 rows x 64 k
// (row = 128B exactly). XOR swizzle: phys col = logical ^ ((row&7)<<4).
// Staging (linear gload_lds, 2 calls/half-tile): call c, thread t -> lds-row
// c*64+(t>>3), phys col (t&7)*16; inverse-swizzled source col
// lb = ((t&7)<<4)^(((t>>3)&7)<<4).
// Per iter (K-tiles t0=2i in dbuf0, t1=2i+1 in dbuf1), 8 phases, each:
// {ds_read subtile (+8 B-reads at P1/P5), stage 1 half-tile, barrier,
//  setprio(1) 16 MFMA setprio(0), [vmcnt @P4/P8], barrier}.
// Stage plan: P1/P2: A0/A1(t1)->dbuf1 (dbuf1-A dead since prev P8);
// P3/P4: B0/B1(t0+2)->dbuf0 (dbuf0-B read only at P1); P5/P6: A(t0+2)->dbuf0
// (dbuf0-A dead after P4); P7/P8: B(t1+2)->dbuf1 (dbuf1-B read only at P5).
// vmcnt(4) @P4: queue = B(t1)[prev P7,P8] A(t1)[P1,P2] B(t0+2)[P3,P4] = 12
// -> retires through A(t1) for P5's reads. vmcnt(4) @P8 retires A(t0+2),
// B(t0+2) for next P1. Tail iters: stages guarded, vmcnt -> 0.
// B-frags (8 v8bf) read once per K-tile and held in regs across P1-P4/P5-P8.
// MFMA C/D: col=lane&15, row=4*(lane>>4)+reg.
// ===========================================================================
#define RD_B8(SLOTB) do { \
  _Pragma("unroll") for (int _j = 0; _j < 4; ++_j) \
  _Pragma("unroll") for (int _kk = 0; _kk < 2; ++_kk) { \
    int _r = (wn & 1) * 64 + _j * 16 + l15; \
    int _c = (_kk * 64 + kq) ^ ((_r & 7) << 4); \
    bfr[_j][_kk] = *(const v8bf*)((SLOTB) + _r * 128 + _c); } } while (0)

#define RD_A4(SLOTA, CL) do { \
  _Pragma("unroll") for (int _f = 0; _f < 2; ++_f) \
  _Pragma("unroll") for (int _kk = 0; _kk < 2; ++_kk) { \
    int _r = (CL) * 32 + _f * 16 + l15; \
    int _c = (_kk * 64 + kq) ^ ((_r & 7) << 4); \
    af[_f][_kk] = *(const v8bf*)((SLOTA) + _r * 128 + _c); } } while (0)

#define MMA16(CL) do { \
  __builtin_amdgcn_s_setprio(1); \
  _Pragma("unroll") for (int _f = 0; _f < 2; ++_f) \
  _Pragma("unroll") for (int _j = 0; _j < 4; ++_j) \
  _Pragma("unroll") for (int _kk = 0; _kk < 2; ++_kk) \
    acc[(CL)*2 + _f][_j] = __builtin_amdgcn_mfma_f32_16x16x32_bf16( \
        af[_f][_kk], bfr[_j][_kk], acc[(CL)*2 + _f][_j], 0, 0, 0); \
  __builtin_amdgcn_s_setprio(0); } while (0)

#define VM4 asm volatile("s_waitcnt vmcnt(4)" ::: "memory")
#define VM0 asm volatile("s_waitcnt vmcnt(0)" ::: "memory")

// The 8-phase iteration body; STGA(h,kt,d)/STGB(h,kt,d) are per-kernel.
#define PH8_ITER(STGA, STGB, NIT)                                        \
  {                                                                      \
    int t1k = 2 * iv + 1, t2k = 2 * iv + 2, t3k = 2 * iv + 3;            \
    bool s2 = (iv + 1 < (NIT));                                          \
    RD_B8(bslot0); RD_A4(aslot0, 0); STGA(0, t1k, 1);                    \
    SBZ; BARR; SBZ; MMA16(0); SBZ; BARR;                                 \
    RD_A4(aslot0, 1); STGA(1, t1k, 1);                                   \
    SBZ; BARR; SBZ; MMA16(1); SBZ; BARR;                                 \
    RD_A4(aslot0, 2); if (s2) STGB(0, t2k, 0);                           \
    SBZ; BARR; SBZ; MMA16(2); SBZ; BARR;                                 \
    RD_A4(aslot0, 3); if (s2) STGB(1, t2k, 0);                           \
    SBZ; BARR; SBZ; MMA16(3); SBZ;                                       \
    if (s2) { VM4; } else { VM0; }                                       \
    BARR;                                                                \
    RD_B8(bslot1); RD_A4(aslot1, 0); if (s2) STGA(0, t2k, 0);            \
    SBZ; BARR; SBZ; MMA16(0); SBZ; BARR;                                 \
    RD_A4(aslot1, 1); if (s2) STGA(1, t2k, 0);                           \
    SBZ; BARR; SBZ; MMA16(1); SBZ; BARR;                                 \
    RD_A4(aslot1, 2); if (s2) STGB(0, t3k, 1);                           \
    SBZ; BARR; SBZ; MMA16(2); SBZ; BARR;                                 \
    RD_A4(aslot1, 3); if (s2) STGB(1, t3k, 1);                           \
    SBZ; BARR; SBZ; MMA16(3); SBZ;                                       \
    if (s2) { VM4; } else { VM0; }                                       \
    BARR;                                                                \
  }

// ---------------------------------------------------------------------------
// G1: 1x1 reduce conv + ReLU, 8-phase. A = interact^T bf16 [m][2304] (4608B
// rows), B = wrb [512][2304]. Grid 256 (128 bx x 2 by). 36 K-tiles -> 18 iters.
// ---------------------------------------------------------------------------
__global__ __launch_bounds__(512, 2)
void k_gemm_reduce(const bf16* __restrict__ A, const bf16* __restrict__ B,
                   bf16* __restrict__ f1, int mbase)
{
  extern __shared__ char lds[];
  const int s = xcd_swz(blockIdx.x, gridDim.x);
  const int by = s & 1, bx = s >> 1;
  const int t = threadIdx.x, lane = t & 63, w = t >> 6;
  const int wm = w >> 2, wn = w & 3;
  const int l15 = lane & 15, kq = (lane >> 4) << 4;
  const int tr64 = t >> 3;
  const int lb = ((t & 7) << 4) ^ ((tr64 & 7) << 4);
  const int t16 = t * 16;
  const char* aslot0 = lds + wm * 16384;
  const char* aslot1 = lds + 65536 + wm * 16384;
  const char* bslot0 = lds + 32768 + (wn >> 1) * 16384;
  const char* bslot1 = lds + 98304 + (wn >> 1) * 16384;
  const char* paA[2][2]; const char* paB[2][2];
  #pragma unroll
  for (int h = 0; h < 2; ++h)
    #pragma unroll
    for (int c = 0; c < 2; ++c) {
      paA[h][c] = (const char*)A + (size_t)(bx * 256 + h * 128 + c * 64 + tr64) * 4608 + lb;
      paB[h][c] = (const char*)B + (size_t)(by * 256 + h * 128 + c * 64 + tr64) * 4608 + lb;
    }
  #define GR_STGA(h, kt, d) do { \
    GLDS16(paA[h][0] + (size_t)(kt) * 128, lds + (d) * 65536 + (h) * 16384 + t16); \
    GLDS16(paA[h][1] + (size_t)(kt) * 128, lds + (d) * 65536 + (h) * 16384 + 8192 + t16); } while (0)
  #define GR_STGB(h, kt, d) do { \
    GLDS16(paB[h][0] + (size_t)(kt) * 128, lds + (d) * 65536 + 32768 + (h) * 16384 + t16); \
    GLDS16(paB[h][1] + (size_t)(kt) * 128, lds + (d) * 65536 + 32768 + (h) * 16384 + 8192 + t16); } while (0)

  f32x4 acc[8][4] = {};
  v8bf bfr[4][2], af[2][2];
  // prologue: B(0), A(0), B(1) staged; tile 0 complete before P1.
  GR_STGB(0, 0, 0); GR_STGB(1, 0, 0); GR_STGA(0, 0, 0); GR_STGA(1, 0, 0);
  GR_STGB(0, 1, 1); GR_STGB(1, 1, 1);
  VM4; BARR;
  for (int iv = 0; iv < 18; ++iv) PH8_ITER(GR_STGA, GR_STGB, 18);
  const int rbase = (lane >> 4) << 2, cl = lane & 15;
  #pragma unroll
  for (int i = 0; i < 8; ++i)
    #pragma unroll
    for (int j = 0; j < 4; ++j)
      #pragma unroll
      for (int r = 0; r < 4; ++r) {
        int row = mbase + bx * 256 + wm * 128 + i * 16 + rbase + r;
        int col = by * 256 + wn * 64 + j * 16 + cl;
        f1[(size_t)row * 512 + col] = (bf16)fmaxf(acc[i][j][r], 0.f);
      }
}

// ---------------------------------------------------------------------------
// G2: 3x3 VALID conv (16x16 -> 14x14), 8-phase. f1 NHWC bf16 -> f14 bf16.
// M=25088 (98 bx) x 2 by = 196 blocks. 72 K-tiles -> 36 iters.
// ---------------------------------------------------------------------------
__global__ __launch_bounds__(512, 2)
void k_conv_rsize(const bf16* __restrict__ f1, const bf16* __restrict__ wt,
                  bf16* __restrict__ f14)
{
  extern __shared__ char lds[];
  const int s = xcd_swz(blockIdx.x, gridDim.x);
  const int by = s & 1, bx = s >> 1;
  const int t = threadIdx.x, lane = t & 63, w = t >> 6;
  const int wm = w >> 2, wn = w & 3;
  const int l15 = lane & 15, kq = (lane >> 4) << 4;
  const int tr64 = t >> 3;
  const int lb = ((t & 7) << 4) ^ ((tr64 & 7) << 4);
  const int t16 = t * 16;
  const char* aslot0 = lds + wm * 16384;
  const char* aslot1 = lds + 65536 + wm * 16384;
  const char* bslot0 = lds + 32768 + (wn >> 1) * 16384;
  const char* bslot1 = lds + 98304 + (wn >> 1) * 16384;
  int ab[2][2]; const char* pwB[2][2];
  #pragma unroll
  for (int h = 0; h < 2; ++h)
    #pragma unroll
    for (int c = 0; c < 2; ++c) {
      int m = bx * 256 + h * 128 + c * 64 + tr64;
      int n = m / 196, rem = m - n * 196;
      int y = rem / 14, x = rem - 14 * (rem / 14);
      ab[h][c] = n * 256 + y * 16 + x;
      pwB[h][c] = (const char*)wt + (size_t)(by * 256 + h * 128 + c * 64 + tr64) * 1024 + lb;
    }
  const char* f1c = (const char*)f1 + lb;
  #define CR_STGA(h, kt, d) do { \
    int _tap = (kt) >> 3, _ko = ((kt) & 7) << 7; \
    int _dy = (_tap * 11) >> 5, _dx = _tap - _dy * 3; \
    int _df = (_dy * 16 + _dx) << 10; \
    GLDS16(f1c + ((size_t)ab[h][0] << 10) + _df + _ko, lds + (d) * 65536 + (h) * 16384 + t16); \
    GLDS16(f1c + ((size_t)ab[h][1] << 10) + _df + _ko, lds + (d) * 65536 + (h) * 16384 + 8192 + t16); } while (0)
  #define CR_STGB(h, kt, d) do { \
    int _tap = (kt) >> 3, _ko = ((kt) & 7) << 7; \
    GLDS16(pwB[h][0] + (size_t)_tap * 524288 + _ko, lds + (d) * 65536 + 32768 + (h) * 16384 + t16); \
    GLDS16(pwB[h][1] + (size_t)_tap * 524288 + _ko, lds + (d) * 65536 + 32768 + (h) * 16384 + 8192 + t16); } while (0)

  f32x4 acc[8][4] = {};
  v8bf bfr[4][2], af[2][2];
  CR_STGB(0, 0, 0); CR_STGB(1, 0, 0); CR_STGA(0, 0, 0); CR_STGA(1, 0, 0);
  CR_STGB(0, 1, 1); CR_STGB(1, 1, 1);
  VM4; BARR;
  for (int iv = 0; iv < 36; ++iv) PH8_ITER(CR_STGA, CR_STGB, 36);
  const int rbase = (lane >> 4) << 2, cl = lane & 15;
  #pragma unroll
  for (int i = 0; i < 8; ++i)
    #pragma unroll
    for (int j = 0; j < 4; ++j)
      #pragma unroll
      for (int r = 0; r < 4; ++r) {
        int row = bx * 256 + wm * 128 + i * 16 + rbase + r;
        int col = by * 256 + wn * 64 + j * 16 + cl;
        f14[(size_t)row * 512 + col] = (bf16)acc[i][j][r];
      }
}

// ===========================================================================
// ring-3 256x128 core (kept for qkv: proven, masked gather)
// ===========================================================================
#define RING_COMPUTE() do { \
  v8bf b_[4], a_[4]; \
  _Pragma("unroll") for (int _j = 0; _j < 4; ++_j) { \
    int _lr = _j * 16 + l15; \
    int _c = (wn * 64 + colb) ^ ((_lr & 7) << 4); \
    b_[_j] = *(const v8bf*)(s0 + 16384 + _lr * 128 + _c); } \
  _Pragma("unroll") for (int _i = 0; _i < 4; ++_i) { \
    int _lr = _i * 16 + l15; \
    int _c = (wm * 64 + colb) ^ ((_lr & 7) << 4); \
    a_[_i] = *(const v8bf*)(s0 + _lr * 128 + _c); } \
  __builtin_amdgcn_s_setprio(1); \
  _Pragma("unroll") for (int _i = 0; _i < 4; ++_i) \
  _Pragma("unroll") for (int _j = 0; _j < 4; ++_j) \
    acc[_i][_j] = __builtin_amdgcn_mfma_f32_16x16x32_bf16(a_[_i], b_[_j], acc[_i][_j], 0, 0, 0); \
  __builtin_amdgcn_s_setprio(0); \
  _Pragma("unroll") for (int _i = 0; _i < 4; ++_i) { \
    int _lr = (_i + 4) * 16 + l15; \
    int _c = (wm * 64 + colb) ^ ((_lr & 7) << 4); \
    a_[_i] = *(const v8bf*)(s0 + _lr * 128 + _c); } \
  __builtin_amdgcn_s_setprio(1); \
  _Pragma("unroll") for (int _i = 0; _i < 4; ++_i) \
  _Pragma("unroll") for (int _j = 0; _j < 4; ++_j) \
    acc[_i + 4][_j] = __builtin_amdgcn_mfma_f32_16x16x32_bf16(a_[_i], b_[_j], acc[_i + 4][_j], 0, 0, 0); \
  __builtin_amdgcn_s_setprio(0); \
} while (0)

#define RING_LOOP(NG, STAGE) do { \
  STAGE(0, s0); STAGE(1, s1); \
  for (int g = 0; g < (NG); ++g) { \
    if (g + 2 < (NG)) { STAGE(g + 2, s2); } \
    if (g + 2 < (NG))       asm volatile("s_waitcnt vmcnt(12)" ::: "memory"); \
    else if (g + 2 == (NG)) asm volatile("s_waitcnt vmcnt(6)" ::: "memory"); \
    else                    asm volatile("s_waitcnt vmcnt(0)" ::: "memory"); \
    __builtin_amdgcn_s_barrier(); \
    __builtin_amdgcn_sched_barrier(0); \
    RING_COMPUTE(); \
    __builtin_amdgcn_sched_barrier(0); \
    __builtin_amdgcn_s_barrier(); \
    char* _tmp = s0; s0 = s1; s1 = s2; s2 = _tmp; \
  } \
} while (0)

// ---------------------------------------------------------------------------
// G4: fused q/k/v 3x3 SAME conv on 7x7 (ring-3). 300 conv blocks + obm tail.
// ---------------------------------------------------------------------------
__global__ __launch_bounds__(256, 2)
void k_conv_qkv(const bf16* __restrict__ fin, const bf16* __restrict__ wt,
                bf16* __restrict__ qkv, const bf16* __restrict__ zp,
                const float* __restrict__ bbox, float* __restrict__ obm)
{
  __shared__ __attribute__((aligned(16))) char ldss[73728];
  char *s0 = ldss, *s1 = ldss + 24576, *s2 = ldss + 49152;
  const int t = threadIdx.x;
  if (blockIdx.x >= 300) {
    int bid = blockIdx.x - 300;
    int n = bid >> 4;
    int c = (bid & 15) * 64 + (t >> 2);
    int seg = t & 3;
    const float4* p4 = (const float4*)(bbox + ((size_t)n * 1024 + c) * 196);
    float sum = 0.f;
    for (int k = seg; k < 49; k += 4) { float4 ww = p4[k]; sum += ww.x + ww.y + ww.z + ww.w; }
    sum += __shfl_xor(sum, 1);
    sum += __shfl_xor(sum, 2);
    if (seg == 0) obm[n * 1024 + c] = sum * (1.f / 196.f);
    return;
  }
  const int s = xcd_swz(blockIdx.x, 300);
  const int q12 = s % 12, bx = s / 12;
  const int tensor = q12 >> 2, byl = q12 & 3;
  const char* wtc = (const char*)wt + (size_t)tensor * 4718592;
  bf16* outp = qkv + (size_t)tensor * 3211264;
  const int lane = t & 63, w = t >> 6;
  const int wm = w >> 1, wn = w & 1;
  const int l15 = lane & 15, colb = (lane >> 4) << 4;
  const int tr = t >> 3;
  const int lb = ((t & 7) << 4) ^ ((tr & 7) << 4);
  const int hi = lb >> 6, kb = lb & 63;
  const int t16 = t * 16;
  int nb[4], py[4], px[4]; const char* pb[2];
  #pragma unroll
  for (int i = 0; i < 4; ++i) {
    int m = bx * 256 + i * 32 + tr + hi * 128;
    if (m > 6271) m = 6271;
    int n = m / 49, rem = m - n * 49;
    nb[i] = n * 49;
    py[i] = rem / 7 - 1;
    px[i] = rem - 7 * (rem / 7) - 1;
  }
  #pragma unroll
  for (int i = 0; i < 2; ++i)
    pb[i] = wtc + (size_t)(byl * 128 + i * 32 + tr + hi * 64) * 1024 + kb;
  const char* finc = (const char*)fin + kb;
  const char* zpc = (const char*)zp;
  #define SQ(kt, ring) do { int _tap = (kt) >> 4, _ko = ((kt) & 15) << 6; \
    int _dy = (_tap * 11) >> 5, _dx = _tap - _dy * 3; \
    _Pragma("unroll") for (int _i = 0; _i < 4; ++_i) { \
      int _iy = py[_i] + _dy, _ix = px[_i] + _dx; \
      const char* _sp = ((unsigned)_iy < 7u && (unsigned)_ix < 7u) \
          ? finc + (size_t)(nb[_i] + _iy * 7 + _ix) * 1024 + _ko : zpc; \
      GLDS16(_sp, (ring) + _i * 4096 + t16); } \
    _Pragma("unroll") for (int _i = 0; _i < 2; ++_i) \
      GLDS16(pb[_i] + (size_t)_tap * 524288 + _ko, (ring) + 16384 + _i * 4096 + t16); } while (0)
  f32x4 acc[8][4] = {};
  RING_LOOP(144, SQ);
  const int rbase = (lane >> 4) << 2, cl = lane & 15;
  #pragma unroll
  for (int i = 0; i < 8; ++i)
    #pragma unroll
    for (int j = 0; j < 4; ++j)
      #pragma unroll
      for (int r = 0; r < 4; ++r) {
        int row = bx * 256 + wm * 128 + i * 16 + rbase + r;
        if (row < 6272) {
          int col = byl * 128 + wn * 64 + j * 16 + cl;
          outp[(size_t)row * 512 + col] = (bf16)acc[i][j][r];
        }
      }
}

// ===========================================================================
// Old 128x128 core (kept for the tiny gemm_s)
// ===========================================================================
__device__ __forceinline__ void tile_compute(const char* ldsA, const char* ldsB,
                                             f32x4 (&acc)[4][4], int wr, int wc, int lane) {
  const int l15 = lane & 15;
  const int colb = (lane >> 4) << 4;
  #pragma unroll
  for (int kk = 0; kk < 2; ++kk) {
    v8bf a[4], b[4];
    #pragma unroll
    for (int i = 0; i < 4; ++i) {
      int ra = wr * 64 + i * 16 + l15;
      int ca = ((kk << 6) | colb) ^ ((ra & 7) << 4);
      a[i] = *(const v8bf*)(ldsA + ra * 128 + ca);
    }
    #pragma unroll
    for (int j = 0; j < 4; ++j) {
      int rb = wc * 64 + j * 16 + l15;
      int cb = ((kk << 6) | colb) ^ ((rb & 7) << 4);
      b[j] = *(const v8bf*)(ldsB + rb * 128 + cb);
    }
    __builtin_amdgcn_s_setprio(1);
    #pragma unroll
    for (int i = 0; i < 4; ++i)
      #pragma unroll
      for (int j = 0; j < 4; ++j)
        acc[i][j] = __builtin_amdgcn_mfma_f32_16x16x32_bf16(a[i], b[j], acc[i][j], 0, 0, 0);
    __builtin_amdgcn_s_setprio(0);
  }
}

#define PIPELINE_LOOP(NK)                                                   \
  stage(0, lds);                                                            \
  stage(1, lds + 32768);                                                    \
  int cur = 0;                                                              \
  for (int ks = 0; ks < (NK) - 1; ++ks) {                                   \
    asm volatile("s_waitcnt vmcnt(8)" ::: "memory");                        \
    __builtin_amdgcn_s_barrier();                                           \
    __builtin_amdgcn_sched_barrier(0);                                      \
    tile_compute(lds + cur * 32768, lds + cur * 32768 + 16384, acc, wr, wc, lane); \
    __builtin_amdgcn_sched_barrier(0);                                      \
    __builtin_amdgcn_s_barrier();                                           \
    __builtin_amdgcn_sched_barrier(0);                                      \
    if (ks + 2 < (NK)) stage(ks + 2, lds + cur * 32768);                    \
    cur ^= 1;                                                               \
  }                                                                         \
  asm volatile("s_waitcnt vmcnt(0)" ::: "memory");                          \
  __builtin_amdgcn_s_barrier();                                             \
  __builtin_amdgcn_sched_barrier(0);                                        \
  tile_compute(lds + cur * 32768, lds + cur * 32768 + 16384, acc, wr, wc, lane);

// G6: w1-conv+ho-mean GEMM, K-split.
__global__ __launch_bounds__(256)
void k_gemm_s(const bf16* __restrict__ A_s, const bf16* __restrict__ w1r,
              float* __restrict__ part)
{
  __shared__ __attribute__((aligned(16))) char lds[65536];
  const int by = blockIdx.x, kspl = blockIdx.y;
  const int t = threadIdx.x, lane = t & 63, w = t >> 6, wr = w >> 1, wc = w & 1;
  const int tr = t >> 3;
  const int cphys = ((t & 7) << 4) ^ ((tr & 7) << 4);
  const char* pa[4]; const char* pb[4];
  #pragma unroll
  for (int i = 0; i < 4; ++i) {
    int r = i * 32 + tr;
    pa[i] = (const char*)A_s + (size_t)r * 9216 + kspl * 2304 + cphys;
    pb[i] = (const char*)w1r + (size_t)(by * 128 + r) * 9216 + kspl * 2304 + cphys;
  }
  const int lo = t * 16;
  auto stage = [&](int ks, char* base) {
    #pragma unroll
    for (int i = 0; i < 4; ++i) GLDS16(pa[i] + ks * 128, base + lo + i * 4096);
    #pragma unroll
    for (int i = 0; i < 4; ++i) GLDS16(pb[i] + ks * 128, base + 16384 + lo + i * 4096);
  };
  f32x4 acc[4][4] = {};
  PIPELINE_LOOP(18)
  const int rb = (lane >> 4) << 2, cl = lane & 15;
  #pragma unroll
  for (int i = 0; i < 4; ++i)
    #pragma unroll
    for (int j = 0; j < 4; ++j)
      #pragma unroll
      for (int r = 0; r < 4; ++r) {
        int row = wr * 64 + i * 16 + rb + r;
        int col = by * 128 + wc * 64 + j * 16 + cl;
        part[(size_t)kspl * 65536 + row * 512 + col] = acc[i][j][r];
      }
}

// K-split reduce + f7m add -> out[:, :512]
__global__ __launch_bounds__(512)
void k_red(const float* __restrict__ part, const float* __restrict__ f7m,
           float* __restrict__ out)
{
  int idx = blockIdx.x * 512 + threadIdx.x;
  float s = part[idx] + part[65536 + idx] + part[131072 + idx] + part[196608 + idx];
  int row = idx >> 9, col = idx & 511;
  out[row * 1024 + col] = s + f7m[idx];
}

// P0: transpose+cast interact (n,2304,256) f32 -> A1 bf16 [(nl*256+p)][2304].
__global__ void k_tin(const float* __restrict__ in, bf16* __restrict__ A1, int n0)
{
  __shared__ float tile[64][36];
  const int k0 = blockIdx.x * 64, p0 = blockIdx.y * 32, nl = blockIdx.z;
  const int n = n0 + nl;
  const int t = threadIdx.x;
  const float* src = in + (size_t)n * 2304 * 256;
  #pragma unroll
  for (int rep = 0; rep < 2; ++rep) {
    int idx = t + rep * 256;
    int row = idx >> 3, c4 = (idx & 7) * 4;
    float4 v = *(const float4*)(src + (size_t)(k0 + row) * 256 + p0 + c4);
    tile[row][c4] = v.x; tile[row][c4 + 1] = v.y;
    tile[row][c4 + 2] = v.z; tile[row][c4 + 3] = v.w;
  }
  __syncthreads();
  const int pl = t >> 3, ke = (t & 7) * 8;
  v8bf o;
  #pragma unroll
  for (int e = 0; e < 8; ++e) o[e] = (bf16)tile[ke + e][pl];
  bf16* dst = A1 + (size_t)nl * 256 * 2304;
  *(v8bf*)(dst + (size_t)(p0 + pl) * 2304 + k0 + ke) = o;
}

// P1+P2 merged weight prep.
__global__ void k_wprep(const float* __restrict__ wred, const float* __restrict__ s0,
                        const float* __restrict__ s1, const float* __restrict__ s2,
                        const float* __restrict__ s3, const float* __restrict__ s4,
                        bf16* __restrict__ wrb, bf16* __restrict__ wt,
                        bf16* __restrict__ w1r)
{
  if (blockIdx.x < 1152) {
    int idx = (blockIdx.x * 256 + threadIdx.x) * 4;
    float4 v = *(const float4*)(wred + idx);
    bf16* d = wrb + idx;
    d[0] = (bf16)v.x; d[1] = (bf16)v.y; d[2] = (bf16)v.z; d[3] = (bf16)v.w;
    return;
  }
  int bid = blockIdx.x - 1152;
  int by = bid >> 10, bx = bid & 1023;
  const float* src;
  switch (by) {
    case 0: src = s0; break; case 1: src = s1; break; case 2: src = s2; break;
    case 3: src = s3; break; default: src = s4; break;
  }
  int q = bx * 256 + threadIdx.x;
  const float* sp = src + (size_t)q * 9;
  float tmp[9];
  #pragma unroll
  for (int e = 0; e < 9; ++e) tmp[e] = sp[e];
  if (by < 4) {
    bf16* dst = wt + (size_t)by * 2359296;
    #pragma unroll
    for (int e = 0; e < 9; ++e) dst[(size_t)e * 262144 + q] = (bf16)tmp[e];
  } else {
    int co = q >> 9, ci = q & 511;
    #pragma unroll
    for (int e = 0; e < 9; ++e) w1r[(size_t)(co * 9 + e) * 512 + ci] = (bf16)tmp[e];
  }
}

// K3: maxpool 3x3 s2 p1, 14x14 -> 7x7, bf16, 2 channels/thread
__global__ void k_pool(const bf16* __restrict__ f14, bf16* __restrict__ f7b)
{
  int idx = blockIdx.x * 256 + threadIdx.x;
  int c2 = idx & 255;
  int pp = idx >> 8;
  int n = pp / 49, p7 = pp - n * 49;
  int y = p7 / 7, x = p7 - 7 * (p7 / 7);
  int y0 = 2 * y - 1, x0 = 2 * x - 1;
  const unsigned* f14u = (const unsigned*)f14;
  float m0 = -3.4e38f, m1 = -3.4e38f;
  #pragma unroll
  for (int dy = 0; dy < 3; ++dy) {
    int iy = y0 + dy; if ((unsigned)iy >= 14u) continue;
    #pragma unroll
    for (int dx = 0; dx < 3; ++dx) {
      int ix = x0 + dx; if ((unsigned)ix >= 14u) continue;
      unsigned vv = f14u[(size_t)(n * 196 + iy * 14 + ix) * 256 + c2];
      m0 = fmaxf(m0, __builtin_bit_cast(float, vv << 16));
      m1 = fmaxf(m1, __builtin_bit_cast(float, vv & 0xffff0000u));
    }
  }
  bf16 b0 = (bf16)m0, b1 = (bf16)m1;
  unsigned pk = (unsigned)__builtin_bit_cast(unsigned short, b0)
              | ((unsigned)__builtin_bit_cast(unsigned short, b1) << 16);
  ((unsigned*)f7b)[idx] = pk;
}

// K5: group attention (8x8 within group, mask from rois)
__global__ __launch_bounds__(256)
void k_attn(const bf16* __restrict__ q, const bf16* __restrict__ k,
            const bf16* __restrict__ v, const float* __restrict__ rois,
            float* __restrict__ virt)
{
  const int p = blockIdx.x, g = blockIdx.y, t = threadIdx.x;
  __shared__ float sS[8][9];
  __shared__ float sP[8][9];
  __shared__ __attribute__((aligned(16))) bf16 sV[8][512];
  {
    int u = t;
    #pragma unroll
    for (int rep = 0; rep < 2; ++rep, u += 256) {
      int j = u >> 6, ch = u & 63;
      *(v8bf*)&sV[j][ch * 8] = *(const v8bf*)(v + ((size_t)(g * 8 + j) * 49 + p) * 512 + ch * 8);
    }
  }
  int pi = t >> 2, ls = t & 3;
  int i = pi >> 3, j = pi & 7;
  const bf16* qi = q + ((size_t)(g * 8 + i) * 49 + p) * 512;
  const bf16* kj = k + ((size_t)(g * 8 + j) * 49 + p) * 512;
  float s = 0.f;
  for (int ch = ls * 16; ch < ls * 16 + 16; ++ch) {
    v8bf a = *(const v8bf*)(qi + ch * 8);
    v8bf b = *(const v8bf*)(kj + ch * 8);
    #pragma unroll
    for (int e = 0; e < 8; ++e) s += (float)a[e] * (float)b[e];
  }
  s += __shfl_xor(s, 1);
  s += __shfl_xor(s, 2);
  if (ls == 0) sS[i][j] = s * 0.04419417382415922f;
  __syncthreads();
  if (t < 8) {
    float gi = rois[(g * 8 + t) * 5];
    float pv[8]; float mx = -3.4e38f;
    #pragma unroll
    for (int jj = 0; jj < 8; ++jj) {
      float gj = rois[(g * 8 + jj) * 5];
      float sv = (gi == gj) ? sS[t][jj] : -1e30f;
      pv[jj] = sv; mx = fmaxf(mx, sv);
    }
    float sum = 0.f;
    #pragma unroll
    for (int jj = 0; jj < 8; ++jj) { float e = expf(pv[jj] - mx); pv[jj] = e; sum += e; }
    float inv = 1.f / sum;
    #pragma unroll
    for (int jj = 0; jj < 8; ++jj) sP[t][jj] = pv[jj] * inv;
  }
  __syncthreads();
  int i2 = t >> 5, c0 = (t & 31) * 16;
  float o[16];
  #pragma unroll
  for (int e = 0; e < 16; ++e) o[e] = 0.f;
  #pragma unroll
  for (int jj = 0; jj < 8; ++jj) {
    float ww = sP[i2][jj];
    v8bf v0 = *(const v8bf*)&sV[jj][c0];
    v8bf v1 = *(const v8bf*)&sV[jj][c0 + 8];
    #pragma unroll
    for (int e = 0; e < 8; ++e) { o[e] += ww * (float)v0[e]; o[8 + e] += ww * (float)v1[e]; }
  }
  float* dst = virt + ((size_t)(g * 8 + i2) * 49 + p) * 512 + c0;
  #pragma unroll
  for (int e = 0; e < 16; ++e) dst[e] = o[e];
}

// K6: fused LN(stats+apply)+windowed-sums (blocks 0..127) and fc (128..255).
__global__ __launch_bounds__(512)
void k_ln_fc(const float* __restrict__ virt, const float* __restrict__ gamma,
             const float* __restrict__ beta, const bf16* __restrict__ f7b,
             bf16* __restrict__ A_s, float* __restrict__ f7m,
             const float* __restrict__ obm, const float* __restrict__ wfc,
             float* __restrict__ out)
{
  const int t = threadIdx.x;
  if (blockIdx.x >= 128) {
    __shared__ float sO[1024];
    int n = blockIdx.x - 128;
    for (int u = t; u < 1024; u += 512) sO[u] = obm[n * 1024 + u];
    __syncthreads();
    const float4* wp = (const float4*)(wfc + (size_t)t * 1024);
    float s = 0.f;
    for (int c4 = 0; c4 < 256; ++c4) {
      float4 w = wp[c4];
      s += w.x * sO[c4 * 4] + w.y * sO[c4 * 4 + 1] + w.z * sO[c4 * 4 + 2] + w.w * sO[c4 * 4 + 3];
    }
    out[n * 1024 + 512 + t] = fmaxf(s, 0.f);
    return;
  }
  const int n = blockIdx.x;
  const float* p = virt + (size_t)n * 25088 + t;
  float xv[49];
  float s1 = 0.f, s2 = 0.f;
  #pragma unroll
  for (int pp = 0; pp < 49; ++pp) {
    float x = p[pp * 512];
    xv[pp] = x; s1 += x; s2 += x * x;
  }
  __shared__ float r1[512], r2[512];
  r1[t] = s1; r2[t] = s2; __syncthreads();
  for (int off = 256; off; off >>= 1) {
    if (t < off) { r1[t] += r1[t + off]; r2[t] += r2[t + off]; }
    __syncthreads();
  }
  float mu = r1[0] * (1.f / 25088.f);
  float var = r2[0] * (1.f / 25088.f) - mu * mu;
  float rstd = rsqrtf(var + 1e-5f);
  float g = gamma[t], be = beta[t];
  const bf16* fp = f7b + (size_t)n * 25088 + t;
  float T = 0, R0 = 0, R6 = 0, C0 = 0, C6 = 0;
  float X00 = 0, X06 = 0, X60 = 0, X66 = 0, F = 0;
  #pragma unroll
  for (int pp = 0; pp < 49; ++pp) {
    const int u = pp / 7, v = pp - 7 * (pp / 7);
    float y = fmaxf((xv[pp] - mu) * rstd * g + be, 0.f);
    T += y;
    if (u == 0) R0 += y;
    if (u == 6) R6 += y;
    if (v == 0) C0 += y;
    if (v == 6) C6 += y;
    if (pp == 0)  X00 = y;
    if (pp == 6)  X06 = y;
    if (pp == 42) X60 = y;
    if (pp == 48) X66 = y;
    F += (float)fp[pp * 512];
  }
  float sv[9] = { T-R6-C6+X66, T-R6, T-R6-C0+X60,
                  T-C6,        T,    T-C0,
                  T-R0-C6+X06, T-R0, T-R0-C0+X00 };
  bf16* Ap = A_s + (size_t)n * 4608 + t;
  #pragma unroll
  for (int tap = 0; tap < 9; ++tap)
    Ap[tap * 512] = (bf16)(sv[tap] * (1.f / 49.f));
  f7m[n * 512 + t] = F * (1.f / 49.f);
}

// ---------------------------------------------------------------------------
extern "C" void kernel_launch(void* const* d_in, const int* in_sizes, int n_in,
                              void* d_out, int out_size, void* d_ws, size_t ws_size,
                              hipStream_t stream) {
  const float* rois     = (const float*)d_in[0];
  const float* interact = (const float*)d_in[1];
  const float* bbox     = (const float*)d_in[2];
  const float* w_reduce = (const float*)d_in[3];
  const float* w_rsize  = (const float*)d_in[4];
  const float* wq       = (const float*)d_in[5];
  const float* wk       = (const float*)d_in[6];
  const float* wv       = (const float*)d_in[7];
  const float* w1       = (const float*)d_in[8];
  const float* gamma    = (const float*)d_in[9];
  const float* beta     = (const float*)d_in[10];
  const float* wfc      = (const float*)d_in[11];
  float* out = (float*)d_out;
  char* ws = (char*)d_ws;

  size_t o = 0;
  auto take = [&](size_t sz) { size_t r = o; o += (sz + 255) & ~(size_t)255; return r; };
  bf16*  wrb   = (bf16*)(ws + take(2359296));
  bf16*  wt    = (bf16*)(ws + take(18874368));
  bf16*  w1r   = (bf16*)(ws + take(4718592));
  char*  Rf1   = ws + take(33554432);
  bf16*  f7b   = (bf16*)(ws + take(6422528));
  float* virt  = (float*)(ws + take(12845056));
  bf16*  A_s   = (bf16*)(ws + take(1179648));
  float* f7m   = (float*)(ws + take(262144));
  float* part  = (float*)(ws + take(1048576));
  float* obm   = (float*)(ws + take(524288));
  bf16*  zp    = (bf16*)(ws + take(256));
  size_t fixedEnd = o;
  const size_t A1_FULL = 150994944;
  bool full = (ws_size >= fixedEnd + A1_FULL);
  bf16* A1  = (bf16*)(ws + fixedEnd);
  bf16* f14 = (bf16*)(ws + fixedEnd);

  bf16* f1 = (bf16*)Rf1;
  bf16* qb = (bf16*)Rf1;
  bf16* kb = qb + 3211264;
  bf16* vb = kb + 3211264;

  hipMemsetAsync(zp, 0, 256, stream);

  k_wprep<<<6272, 256, 0, stream>>>(w_reduce, w_rsize, wq, wk, wv, w1, wrb, wt, w1r);

  if (full) {
    k_tin<<<dim3(36, 8, 128), 256, 0, stream>>>(interact, A1, 0);
    k_gemm_reduce<<<256, 512, 131072, stream>>>(A1, wrb, f1, 0);
  } else {
    for (int ch = 0; ch < 4; ++ch) {
      k_tin<<<dim3(36, 8, 32), 256, 0, stream>>>(interact, A1, ch * 32);
      k_gemm_reduce<<<64, 512, 131072, stream>>>(A1, wrb, f1, ch * 8192);
    }
  }

  k_conv_rsize<<<196, 512, 131072, stream>>>(f1, wt, f14);
  k_pool<<<6272, 256, 0, stream>>>(f14, f7b);

  k_conv_qkv<<<2348, 256, 0, stream>>>(f7b, wt + (size_t)1 * 2359296, qb, zp, bbox, obm);

  k_attn<<<dim3(49, 16), 256, 0, stream>>>(qb, kb, vb, rois, virt);

  k_ln_fc<<<256, 512, 0, stream>>>(virt, gamma, beta, f7b, A_s, f7m, obm, wfc, out);

  k_gemm_s<<<dim3(4, 4), 256, 0, stream>>>(A_s, w1r, part);
  k_red<<<128, 512, 0, stream>>>(part, f7m, out);
}

// Round 11
// 514.617 us; speedup vs baseline: 1.7794x; 1.0033x over previous
//
#include <hip/hip_runtime.h>
#include <hip/hip_bf16.h>
#include <math.h>

typedef __bf16 bf16;
typedef __bf16 v8bf __attribute__((ext_vector_type(8)));
typedef float f32x4 __attribute__((ext_vector_type(4)));

// async global->LDS, 16B per lane (per-thread LDS offset is t*16, lane-linear).
#define GLDS16(g, l) __builtin_amdgcn_global_load_lds( \
    (const __attribute__((address_space(1))) void*)(g), \
    (__attribute__((address_space(3))) void*)(l), 16, 0, 0)

// bijective XCD-chunk swizzle (m204 variant, works for any nwg)
__device__ __forceinline__ int xcd_swz(int bid, int nwg) {
  int xcd = bid & 7, off = bid >> 3;
  int q = nwg >> 3, r = nwg & 7;
  return (xcd < r ? xcd * (q + 1) : r * (q + 1) + (xcd - r) * q) + off;
}

#define SBZ __builtin_amdgcn_sched_barrier(0)
#define BARR __builtin_amdgcn_s_barrier()

// ===========================================================================
// 8-phase 256x256 core (m201-style). 512 thr = 8 waves (2M x 4N), per-wave
// output 128x64. BK=64 per K-tile. LDS (dynamic, 128KB) = 2 dbuf x
// {A-half0, A-half1, B-half0, B-half1} x 16KB. Half-tile = 128 rows x 64 k
// (row = 128B exactly). XOR swizzle: phys col = logical ^ ((row&7)<<4).
// Staging (linear gload_lds, 2 calls/half-tile): call c, thread t -> lds-row
// c*64+(t>>3), phys col (t&7)*16; inverse-swizzled source col
// lb = ((t&7)<<4)^(((t>>3)&7)<<4).
// Per iter (K-tiles t0=2i dbuf0, t1=2i+1 dbuf1), 8 phases each:
// {ds_read subtile (+8 B-reads at P1/P5), stage 1 half-tile, barrier,
//  setprio(1) 16 MFMA setprio(0), [vmcnt @P4/P8], barrier}.
// vmcnt(4) @P4 retires B(t1),A(t1); @P8 retires A(t0+2),B(t0+2). Tail -> 0.
// MFMA C/D: col=lane&15, row=4*(lane>>4)+reg.
// ===========================================================================
#define RD_B8(SLOTB) do { \
  _Pragma("unroll") for (int _j = 0; _j < 4; ++_j) \
  _Pragma("unroll") for (int _kk = 0; _kk < 2; ++_kk) { \
    int _r = (wn & 1) * 64 + _j * 16 + l15; \
    int _c = (_kk * 64 + kq) ^ ((_r & 7) << 4); \
    bfr[_j][_kk] = *(const v8bf*)((SLOTB) + _r * 128 + _c); } } while (0)

#define RD_A4(SLOTA, CL) do { \
  _Pragma("unroll") for (int _f = 0; _f < 2; ++_f) \
  _Pragma("unroll") for (int _kk = 0; _kk < 2; ++_kk) { \
    int _r = (CL) * 32 + _f * 16 + l15; \
    int _c = (_kk * 64 + kq) ^ ((_r & 7) << 4); \
    af[_f][_kk] = *(const v8bf*)((SLOTA) + _r * 128 + _c); } } while (0)

#define MMA16(CL) do { \
  __builtin_amdgcn_s_setprio(1); \
  _Pragma("unroll") for (int _f = 0; _f < 2; ++_f) \
  _Pragma("unroll") for (int _j = 0; _j < 4; ++_j) \
  _Pragma("unroll") for (int _kk = 0; _kk < 2; ++_kk) \
    acc[(CL)*2 + _f][_j] = __builtin_amdgcn_mfma_f32_16x16x32_bf16( \
        af[_f][_kk], bfr[_j][_kk], acc[(CL)*2 + _f][_j], 0, 0, 0); \
  __builtin_amdgcn_s_setprio(0); } while (0)

#define VM4 asm volatile("s_waitcnt vmcnt(4)" ::: "memory")
#define VM0 asm volatile("s_waitcnt vmcnt(0)" ::: "memory")

// The 8-phase iteration body; STGA(h,kt,d)/STGB(h,kt,d) are per-kernel.
#define PH8_ITER(STGA, STGB, NIT)                                        \
  {                                                                      \
    int t1k = 2 * iv + 1, t2k = 2 * iv + 2, t3k = 2 * iv + 3;            \
    bool s2 = (iv + 1 < (NIT));                                          \
    RD_B8(bslot0); RD_A4(aslot0, 0); STGA(0, t1k, 1);                    \
    SBZ; BARR; SBZ; MMA16(0); SBZ; BARR;                                 \
    RD_A4(aslot0, 1); STGA(1, t1k, 1);                                   \
    SBZ; BARR; SBZ; MMA16(1); SBZ; BARR;                                 \
    RD_A4(aslot0, 2); if (s2) STGB(0, t2k, 0);                           \
    SBZ; BARR; SBZ; MMA16(2); SBZ; BARR;                                 \
    RD_A4(aslot0, 3); if (s2) STGB(1, t2k, 0);                           \
    SBZ; BARR; SBZ; MMA16(3); SBZ;                                       \
    if (s2) { VM4; } else { VM0; }                                       \
    BARR;                                                                \
    RD_B8(bslot1); RD_A4(aslot1, 0); if (s2) STGA(0, t2k, 0);            \
    SBZ; BARR; SBZ; MMA16(0); SBZ; BARR;                                 \
    RD_A4(aslot1, 1); if (s2) STGA(1, t2k, 0);                           \
    SBZ; BARR; SBZ; MMA16(1); SBZ; BARR;                                 \
    RD_A4(aslot1, 2); if (s2) STGB(0, t3k, 1);                           \
    SBZ; BARR; SBZ; MMA16(2); SBZ; BARR;                                 \
    RD_A4(aslot1, 3); if (s2) STGB(1, t3k, 1);                           \
    SBZ; BARR; SBZ; MMA16(3); SBZ;                                       \
    if (s2) { VM4; } else { VM0; }                                       \
    BARR;                                                                \
  }

// ---------------------------------------------------------------------------
// G1: 1x1 reduce conv + ReLU, 8-phase. A = interact^T bf16 [m][2304] (4608B
// rows), B = wrb [512][2304]. Grid 256 (128 bx x 2 by). 36 K-tiles -> 18 iters.
// ---------------------------------------------------------------------------
__global__ __launch_bounds__(512, 2)
void k_gemm_reduce(const bf16* __restrict__ A, const bf16* __restrict__ B,
                   bf16* __restrict__ f1, int mbase)
{
  extern __shared__ char lds[];
  const int s = xcd_swz(blockIdx.x, gridDim.x);
  const int by = s & 1, bx = s >> 1;
  const int t = threadIdx.x, lane = t & 63, w = t >> 6;
  const int wm = w >> 2, wn = w & 3;
  const int l15 = lane & 15, kq = (lane >> 4) << 4;
  const int tr64 = t >> 3;
  const int lb = ((t & 7) << 4) ^ ((tr64 & 7) << 4);
  const int t16 = t * 16;
  const char* aslot0 = lds + wm * 16384;
  const char* aslot1 = lds + 65536 + wm * 16384;
  const char* bslot0 = lds + 32768 + (wn >> 1) * 16384;
  const char* bslot1 = lds + 98304 + (wn >> 1) * 16384;
  const char* paA[2][2]; const char* paB[2][2];
  #pragma unroll
  for (int h = 0; h < 2; ++h)
    #pragma unroll
    for (int c = 0; c < 2; ++c) {
      paA[h][c] = (const char*)A + (size_t)(bx * 256 + h * 128 + c * 64 + tr64) * 4608 + lb;
      paB[h][c] = (const char*)B + (size_t)(by * 256 + h * 128 + c * 64 + tr64) * 4608 + lb;
    }
  #define GR_STGA(h, kt, d) do { \
    GLDS16(paA[h][0] + (size_t)(kt) * 128, lds + (d) * 65536 + (h) * 16384 + t16); \
    GLDS16(paA[h][1] + (size_t)(kt) * 128, lds + (d) * 65536 + (h) * 16384 + 8192 + t16); } while (0)
  #define GR_STGB(h, kt, d) do { \
    GLDS16(paB[h][0] + (size_t)(kt) * 128, lds + (d) * 65536 + 32768 + (h) * 16384 + t16); \
    GLDS16(paB[h][1] + (size_t)(kt) * 128, lds + (d) * 65536 + 32768 + (h) * 16384 + 8192 + t16); } while (0)

  f32x4 acc[8][4] = {};
  v8bf bfr[4][2], af[2][2];
  GR_STGB(0, 0, 0); GR_STGB(1, 0, 0); GR_STGA(0, 0, 0); GR_STGA(1, 0, 0);
  GR_STGB(0, 1, 1); GR_STGB(1, 1, 1);
  VM4; BARR;
  for (int iv = 0; iv < 18; ++iv) PH8_ITER(GR_STGA, GR_STGB, 18);
  const int rbase = (lane >> 4) << 2, cl = lane & 15;
  #pragma unroll
  for (int i = 0; i < 8; ++i)
    #pragma unroll
    for (int j = 0; j < 4; ++j)
      #pragma unroll
      for (int r = 0; r < 4; ++r) {
        int row = mbase + bx * 256 + wm * 128 + i * 16 + rbase + r;
        int col = by * 256 + wn * 64 + j * 16 + cl;
        f1[(size_t)row * 512 + col] = (bf16)fmaxf(acc[i][j][r], 0.f);
      }
}

// ---------------------------------------------------------------------------
// G2: 3x3 VALID conv (16x16 -> 14x14), 8-phase. f1 NHWC bf16 -> f14 bf16.
// M=25088 (98 bx) x 2 by = 196 blocks. 72 K-tiles -> 36 iters.
// ---------------------------------------------------------------------------
__global__ __launch_bounds__(512, 2)
void k_conv_rsize(const bf16* __restrict__ f1, const bf16* __restrict__ wt,
                  bf16* __restrict__ f14)
{
  extern __shared__ char lds[];
  const int s = xcd_swz(blockIdx.x, gridDim.x);
  const int by = s & 1, bx = s >> 1;
  const int t = threadIdx.x, lane = t & 63, w = t >> 6;
  const int wm = w >> 2, wn = w & 3;
  const int l15 = lane & 15, kq = (lane >> 4) << 4;
  const int tr64 = t >> 3;
  const int lb = ((t & 7) << 4) ^ ((tr64 & 7) << 4);
  const int t16 = t * 16;
  const char* aslot0 = lds + wm * 16384;
  const char* aslot1 = lds + 65536 + wm * 16384;
  const char* bslot0 = lds + 32768 + (wn >> 1) * 16384;
  const char* bslot1 = lds + 98304 + (wn >> 1) * 16384;
  int ab[2][2]; const char* pwB[2][2];
  #pragma unroll
  for (int h = 0; h < 2; ++h)
    #pragma unroll
    for (int c = 0; c < 2; ++c) {
      int m = bx * 256 + h * 128 + c * 64 + tr64;
      int n = m / 196, rem = m - n * 196;
      int y = rem / 14, x = rem - 14 * (rem / 14);
      ab[h][c] = n * 256 + y * 16 + x;
      pwB[h][c] = (const char*)wt + (size_t)(by * 256 + h * 128 + c * 64 + tr64) * 1024 + lb;
    }
  const char* f1c = (const char*)f1 + lb;
  #define CR_STGA(h, kt, d) do { \
    int _tap = (kt) >> 3, _ko = ((kt) & 7) << 7; \
    int _dy = (_tap * 11) >> 5, _dx = _tap - _dy * 3; \
    int _df = (_dy * 16 + _dx) << 10; \
    GLDS16(f1c + ((size_t)ab[h][0] << 10) + _df + _ko, lds + (d) * 65536 + (h) * 16384 + t16); \
    GLDS16(f1c + ((size_t)ab[h][1] << 10) + _df + _ko, lds + (d) * 65536 + (h) * 16384 + 8192 + t16); } while (0)
  #define CR_STGB(h, kt, d) do { \
    int _tap = (kt) >> 3, _ko = ((kt) & 7) << 7; \
    GLDS16(pwB[h][0] + (size_t)_tap * 524288 + _ko, lds + (d) * 65536 + 32768 + (h) * 16384 + t16); \
    GLDS16(pwB[h][1] + (size_t)_tap * 524288 + _ko, lds + (d) * 65536 + 32768 + (h) * 16384 + 8192 + t16); } while (0)

  f32x4 acc[8][4] = {};
  v8bf bfr[4][2], af[2][2];
  CR_STGB(0, 0, 0); CR_STGB(1, 0, 0); CR_STGA(0, 0, 0); CR_STGA(1, 0, 0);
  CR_STGB(0, 1, 1); CR_STGB(1, 1, 1);
  VM4; BARR;
  for (int iv = 0; iv < 36; ++iv) PH8_ITER(CR_STGA, CR_STGB, 36);
  const int rbase = (lane >> 4) << 2, cl = lane & 15;
  #pragma unroll
  for (int i = 0; i < 8; ++i)
    #pragma unroll
    for (int j = 0; j < 4; ++j)
      #pragma unroll
      for (int r = 0; r < 4; ++r) {
        int row = bx * 256 + wm * 128 + i * 16 + rbase + r;
        int col = by * 256 + wn * 64 + j * 16 + cl;
        f14[(size_t)row * 512 + col] = (bf16)acc[i][j][r];
      }
}

// ---------------------------------------------------------------------------
// G4: fused q/k/v 3x3 SAME conv on 7x7, 8-phase. M=6272 (25 bx, masked tail),
// N=1536 (6 by: tensor = by>>1, col-half = by&1) -> 150 conv blocks; blocks
// 150..1173 = obm mean (512 thr: 8 cgroups x 128 ch). 72 K-tiles -> 36 iters.
// A-gather boundary -> zp (lane-uniform 16B zero source).
// ---------------------------------------------------------------------------
__global__ __launch_bounds__(512, 2)
void k_conv_qkv(const bf16* __restrict__ fin, const bf16* __restrict__ wt,
                bf16* __restrict__ qkv, const bf16* __restrict__ zp,
                const float* __restrict__ bbox, float* __restrict__ obm)
{
  extern __shared__ char lds[];
  const int t = threadIdx.x;
  if (blockIdx.x >= 150) {
    int bid = blockIdx.x - 150;           // 1024 blocks: 128 n x 8 cgroups
    int n = bid >> 3;
    int c = (bid & 7) * 128 + (t >> 2);
    int seg = t & 3;
    const float4* p4 = (const float4*)(bbox + ((size_t)n * 1024 + c) * 196);
    float sum = 0.f;
    for (int k = seg; k < 49; k += 4) { float4 ww = p4[k]; sum += ww.x + ww.y + ww.z + ww.w; }
    sum += __shfl_xor(sum, 1);
    sum += __shfl_xor(sum, 2);
    if (seg == 0) obm[n * 1024 + c] = sum * (1.f / 196.f);
    return;
  }
  const int s = xcd_swz(blockIdx.x, 150);
  const int q6 = s % 6, bx = s / 6;
  const int tensor = q6 >> 1, byh = q6 & 1;
  const char* wtc = (const char*)wt + (size_t)tensor * 4718592;
  bf16* outp = qkv + (size_t)tensor * 3211264;
  const int lane = t & 63, w = t >> 6;
  const int wm = w >> 2, wn = w & 3;
  const int l15 = lane & 15, kq = (lane >> 4) << 4;
  const int tr64 = t >> 3;
  const int lb = ((t & 7) << 4) ^ ((tr64 & 7) << 4);
  const int t16 = t * 16;
  const char* aslot0 = lds + wm * 16384;
  const char* aslot1 = lds + 65536 + wm * 16384;
  const char* bslot0 = lds + 32768 + (wn >> 1) * 16384;
  const char* bslot1 = lds + 98304 + (wn >> 1) * 16384;
  int nb[2][2], py[2][2], px[2][2]; const char* pwB[2][2];
  #pragma unroll
  for (int h = 0; h < 2; ++h)
    #pragma unroll
    for (int c = 0; c < 2; ++c) {
      int m = bx * 256 + h * 128 + c * 64 + tr64;
      if (m > 6271) m = 6271;
      int n = m / 49, rem = m - n * 49;
      nb[h][c] = n * 49;
      py[h][c] = rem / 7 - 1;
      px[h][c] = rem - 7 * (rem / 7) - 1;
      pwB[h][c] = wtc + (size_t)(byh * 256 + h * 128 + c * 64 + tr64) * 1024 + lb;
    }
  const char* finc = (const char*)fin + lb;
  const char* zpc = (const char*)zp;
  #define QK_STGA(h, kt, d) do { \
    int _tap = (kt) >> 3, _ko = ((kt) & 7) << 7; \
    int _dy = (_tap * 11) >> 5, _dx = _tap - _dy * 3; \
    _Pragma("unroll") for (int _c = 0; _c < 2; ++_c) { \
      int _iy = py[h][_c] + _dy, _ix = px[h][_c] + _dx; \
      const char* _sp = ((unsigned)_iy < 7u && (unsigned)_ix < 7u) \
          ? finc + (size_t)(nb[h][_c] + _iy * 7 + _ix) * 1024 + _ko : zpc; \
      GLDS16(_sp, lds + (d) * 65536 + (h) * 16384 + _c * 8192 + t16); } } while (0)
  #define QK_STGB(h, kt, d) do { \
    int _tap = (kt) >> 3, _ko = ((kt) & 7) << 7; \
    GLDS16(pwB[h][0] + (size_t)_tap * 524288 + _ko, lds + (d) * 65536 + 32768 + (h) * 16384 + t16); \
    GLDS16(pwB[h][1] + (size_t)_tap * 524288 + _ko, lds + (d) * 65536 + 32768 + (h) * 16384 + 8192 + t16); } while (0)

  f32x4 acc[8][4] = {};
  v8bf bfr[4][2], af[2][2];
  QK_STGB(0, 0, 0); QK_STGB(1, 0, 0); QK_STGA(0, 0, 0); QK_STGA(1, 0, 0);
  QK_STGB(0, 1, 1); QK_STGB(1, 1, 1);
  VM4; BARR;
  for (int iv = 0; iv < 36; ++iv) PH8_ITER(QK_STGA, QK_STGB, 36);
  const int rbase = (lane >> 4) << 2, cl = lane & 15;
  #pragma unroll
  for (int i = 0; i < 8; ++i)
    #pragma unroll
    for (int j = 0; j < 4; ++j)
      #pragma unroll
      for (int r = 0; r < 4; ++r) {
        int row = bx * 256 + wm * 128 + i * 16 + rbase + r;
        if (row < 6272) {
          int col = byh * 256 + wn * 64 + j * 16 + cl;
          outp[(size_t)row * 512 + col] = (bf16)acc[i][j][r];
        }
      }
}

// ===========================================================================
// Old 128x128 core (kept for the tiny gemm_s)
// ===========================================================================
__device__ __forceinline__ void tile_compute(const char* ldsA, const char* ldsB,
                                             f32x4 (&acc)[4][4], int wr, int wc, int lane) {
  const int l15 = lane & 15;
  const int colb = (lane >> 4) << 4;
  #pragma unroll
  for (int kk = 0; kk < 2; ++kk) {
    v8bf a[4], b[4];
    #pragma unroll
    for (int i = 0; i < 4; ++i) {
      int ra = wr * 64 + i * 16 + l15;
      int ca = ((kk << 6) | colb) ^ ((ra & 7) << 4);
      a[i] = *(const v8bf*)(ldsA + ra * 128 + ca);
    }
    #pragma unroll
    for (int j = 0; j < 4; ++j) {
      int rb = wc * 64 + j * 16 + l15;
      int cb = ((kk << 6) | colb) ^ ((rb & 7) << 4);
      b[j] = *(const v8bf*)(ldsB + rb * 128 + cb);
    }
    __builtin_amdgcn_s_setprio(1);
    #pragma unroll
    for (int i = 0; i < 4; ++i)
      #pragma unroll
      for (int j = 0; j < 4; ++j)
        acc[i][j] = __builtin_amdgcn_mfma_f32_16x16x32_bf16(a[i], b[j], acc[i][j], 0, 0, 0);
    __builtin_amdgcn_s_setprio(0);
  }
}

#define PIPELINE_LOOP(NK)                                                   \
  stage(0, lds);                                                            \
  stage(1, lds + 32768);                                                    \
  int cur = 0;                                                              \
  for (int ks = 0; ks < (NK) - 1; ++ks) {                                   \
    asm volatile("s_waitcnt vmcnt(8)" ::: "memory");                        \
    __builtin_amdgcn_s_barrier();                                           \
    __builtin_amdgcn_sched_barrier(0);                                      \
    tile_compute(lds + cur * 32768, lds + cur * 32768 + 16384, acc, wr, wc, lane); \
    __builtin_amdgcn_sched_barrier(0);                                      \
    __builtin_amdgcn_s_barrier();                                           \
    __builtin_amdgcn_sched_barrier(0);                                      \
    if (ks + 2 < (NK)) stage(ks + 2, lds + cur * 32768);                    \
    cur ^= 1;                                                               \
  }                                                                         \
  asm volatile("s_waitcnt vmcnt(0)" ::: "memory");                          \
  __builtin_amdgcn_s_barrier();                                             \
  __builtin_amdgcn_sched_barrier(0);                                        \
  tile_compute(lds + cur * 32768, lds + cur * 32768 + 16384, acc, wr, wc, lane);

// G6: w1-conv+ho-mean GEMM, K-split; partials atomically added onto
// out[:, :512] (base = f7 mean, written by k_ln_fc beforehand).
__global__ __launch_bounds__(256)
void k_gemm_s(const bf16* __restrict__ A_s, const bf16* __restrict__ w1r,
              float* __restrict__ out)
{
  __shared__ __attribute__((aligned(16))) char lds[65536];
  const int by = blockIdx.x, kspl = blockIdx.y;
  const int t = threadIdx.x, lane = t & 63, w = t >> 6, wr = w >> 1, wc = w & 1;
  const int tr = t >> 3;
  const int cphys = ((t & 7) << 4) ^ ((tr & 7) << 4);
  const char* pa[4]; const char* pb[4];
  #pragma unroll
  for (int i = 0; i < 4; ++i) {
    int r = i * 32 + tr;
    pa[i] = (const char*)A_s + (size_t)r * 9216 + kspl * 2304 + cphys;
    pb[i] = (const char*)w1r + (size_t)(by * 128 + r) * 9216 + kspl * 2304 + cphys;
  }
  const int lo = t * 16;
  auto stage = [&](int ks, char* base) {
    #pragma unroll
    for (int i = 0; i < 4; ++i) GLDS16(pa[i] + ks * 128, base + lo + i * 4096);
    #pragma unroll
    for (int i = 0; i < 4; ++i) GLDS16(pb[i] + ks * 128, base + 16384 + lo + i * 4096);
  };
  f32x4 acc[4][4] = {};
  PIPELINE_LOOP(18)
  const int rb = (lane >> 4) << 2, cl = lane & 15;
  #pragma unroll
  for (int i = 0; i < 4; ++i)
    #pragma unroll
    for (int j = 0; j < 4; ++j)
      #pragma unroll
      for (int r = 0; r < 4; ++r) {
        int row = wr * 64 + i * 16 + rb + r;
        int col = by * 128 + wc * 64 + j * 16 + cl;
        atomicAdd(&out[(size_t)row * 1024 + col], acc[i][j][r]);
      }
}

// P0: transpose+cast interact (n,2304,256) f32 -> A1 bf16 [(nl*256+p)][2304].
__global__ void k_tin(const float* __restrict__ in, bf16* __restrict__ A1, int n0)
{
  __shared__ float tile[64][36];
  const int k0 = blockIdx.x * 64, p0 = blockIdx.y * 32, nl = blockIdx.z;
  const int n = n0 + nl;
  const int t = threadIdx.x;
  const float* src = in + (size_t)n * 2304 * 256;
  #pragma unroll
  for (int rep = 0; rep < 2; ++rep) {
    int idx = t + rep * 256;
    int row = idx >> 3, c4 = (idx & 7) * 4;
    float4 v = *(const float4*)(src + (size_t)(k0 + row) * 256 + p0 + c4);
    tile[row][c4] = v.x; tile[row][c4 + 1] = v.y;
    tile[row][c4 + 2] = v.z; tile[row][c4 + 3] = v.w;
  }
  __syncthreads();
  const int pl = t >> 3, ke = (t & 7) * 8;
  v8bf o;
  #pragma unroll
  for (int e = 0; e < 8; ++e) o[e] = (bf16)tile[ke + e][pl];
  bf16* dst = A1 + (size_t)nl * 256 * 2304;
  *(v8bf*)(dst + (size_t)(p0 + pl) * 2304 + k0 + ke) = o;
}

// P1+P2 merged weight prep.
__global__ void k_wprep(const float* __restrict__ wred, const float* __restrict__ s0,
                        const float* __restrict__ s1, const float* __restrict__ s2,
                        const float* __restrict__ s3, const float* __restrict__ s4,
                        bf16* __restrict__ wrb, bf16* __restrict__ wt,
                        bf16* __restrict__ w1r)
{
  if (blockIdx.x < 1152) {
    int idx = (blockIdx.x * 256 + threadIdx.x) * 4;
    float4 v = *(const float4*)(wred + idx);
    bf16* d = wrb + idx;
    d[0] = (bf16)v.x; d[1] = (bf16)v.y; d[2] = (bf16)v.z; d[3] = (bf16)v.w;
    return;
  }
  int bid = blockIdx.x - 1152;
  int by = bid >> 10, bx = bid & 1023;
  const float* src;
  switch (by) {
    case 0: src = s0; break; case 1: src = s1; break; case 2: src = s2; break;
    case 3: src = s3; break; default: src = s4; break;
  }
  int q = bx * 256 + threadIdx.x;
  const float* sp = src + (size_t)q * 9;
  float tmp[9];
  #pragma unroll
  for (int e = 0; e < 9; ++e) tmp[e] = sp[e];
  if (by < 4) {
    bf16* dst = wt + (size_t)by * 2359296;
    #pragma unroll
    for (int e = 0; e < 9; ++e) dst[(size_t)e * 262144 + q] = (bf16)tmp[e];
  } else {
    int co = q >> 9, ci = q & 511;
    #pragma unroll
    for (int e = 0; e < 9; ++e) w1r[(size_t)(co * 9 + e) * 512 + ci] = (bf16)tmp[e];
  }
}

// K3: maxpool 3x3 s2 p1, 14x14 -> 7x7, bf16, 2 channels/thread
__global__ void k_pool(const bf16* __restrict__ f14, bf16* __restrict__ f7b)
{
  int idx = blockIdx.x * 256 + threadIdx.x;
  int c2 = idx & 255;
  int pp = idx >> 8;
  int n = pp / 49, p7 = pp - n * 49;
  int y = p7 / 7, x = p7 - 7 * (p7 / 7);
  int y0 = 2 * y - 1, x0 = 2 * x - 1;
  const unsigned* f14u = (const unsigned*)f14;
  float m0 = -3.4e38f, m1 = -3.4e38f;
  #pragma unroll
  for (int dy = 0; dy < 3; ++dy) {
    int iy = y0 + dy; if ((unsigned)iy >= 14u) continue;
    #pragma unroll
    for (int dx = 0; dx < 3; ++dx) {
      int ix = x0 + dx; if ((unsigned)ix >= 14u) continue;
      unsigned vv = f14u[(size_t)(n * 196 + iy * 14 + ix) * 256 + c2];
      m0 = fmaxf(m0, __builtin_bit_cast(float, vv << 16));
      m1 = fmaxf(m1, __builtin_bit_cast(float, vv & 0xffff0000u));
    }
  }
  bf16 b0 = (bf16)m0, b1 = (bf16)m1;
  unsigned pk = (unsigned)__builtin_bit_cast(unsigned short, b0)
              | ((unsigned)__builtin_bit_cast(unsigned short, b1) << 16);
  ((unsigned*)f7b)[idx] = pk;
}

// K5: group attention (8x8 within group, mask from rois)
__global__ __launch_bounds__(256)
void k_attn(const bf16* __restrict__ q, const bf16* __restrict__ k,
            const bf16* __restrict__ v, const float* __restrict__ rois,
            float* __restrict__ virt)
{
  const int p = blockIdx.x, g = blockIdx.y, t = threadIdx.x;
  __shared__ float sS[8][9];
  __shared__ float sP[8][9];
  __shared__ __attribute__((aligned(16))) bf16 sV[8][512];
  {
    int u = t;
    #pragma unroll
    for (int rep = 0; rep < 2; ++rep, u += 256) {
      int j = u >> 6, ch = u & 63;
      *(v8bf*)&sV[j][ch * 8] = *(const v8bf*)(v + ((size_t)(g * 8 + j) * 49 + p) * 512 + ch * 8);
    }
  }
  int pi = t >> 2, ls = t & 3;
  int i = pi >> 3, j = pi & 7;
  const bf16* qi = q + ((size_t)(g * 8 + i) * 49 + p) * 512;
  const bf16* kj = k + ((size_t)(g * 8 + j) * 49 + p) * 512;
  float s = 0.f;
  for (int ch = ls * 16; ch < ls * 16 + 16; ++ch) {
    v8bf a = *(const v8bf*)(qi + ch * 8);
    v8bf b = *(const v8bf*)(kj + ch * 8);
    #pragma unroll
    for (int e = 0; e < 8; ++e) s += (float)a[e] * (float)b[e];
  }
  s += __shfl_xor(s, 1);
  s += __shfl_xor(s, 2);
  if (ls == 0) sS[i][j] = s * 0.04419417382415922f;
  __syncthreads();
  if (t < 8) {
    float gi = rois[(g * 8 + t) * 5];
    float pv[8]; float mx = -3.4e38f;
    #pragma unroll
    for (int jj = 0; jj < 8; ++jj) {
      float gj = rois[(g * 8 + jj) * 5];
      float sv = (gi == gj) ? sS[t][jj] : -1e30f;
      pv[jj] = sv; mx = fmaxf(mx, sv);
    }
    float sum = 0.f;
    #pragma unroll
    for (int jj = 0; jj < 8; ++jj) { float e = expf(pv[jj] - mx); pv[jj] = e; sum += e; }
    float inv = 1.f / sum;
    #pragma unroll
    for (int jj = 0; jj < 8; ++jj) sP[t][jj] = pv[jj] * inv;
  }
  __syncthreads();
  int i2 = t >> 5, c0 = (t & 31) * 16;
  float o[16];
  #pragma unroll
  for (int e = 0; e < 16; ++e) o[e] = 0.f;
  #pragma unroll
  for (int jj = 0; jj < 8; ++jj) {
    float ww = sP[i2][jj];
    v8bf v0 = *(const v8bf*)&sV[jj][c0];
    v8bf v1 = *(const v8bf*)&sV[jj][c0 + 8];
    #pragma unroll
    for (int e = 0; e < 8; ++e) { o[e] += ww * (float)v0[e]; o[8 + e] += ww * (float)v1[e]; }
  }
  float* dst = virt + ((size_t)(g * 8 + i2) * 49 + p) * 512 + c0;
  #pragma unroll
  for (int e = 0; e < 16; ++e) dst[e] = o[e];
}

// K6: fused LN(stats+apply)+windowed-sums (blocks 0..127; writes the f7 mean
// base directly into out[:, :512]) and fc (blocks 128..255).
__global__ __launch_bounds__(512)
void k_ln_fc(const float* __restrict__ virt, const float* __restrict__ gamma,
             const float* __restrict__ beta, const bf16* __restrict__ f7b,
             bf16* __restrict__ A_s,
             const float* __restrict__ obm, const float* __restrict__ wfc,
             float* __restrict__ out)
{
  const int t = threadIdx.x;
  if (blockIdx.x >= 128) {
    __shared__ float sO[1024];
    int n = blockIdx.x - 128;
    for (int u = t; u < 1024; u += 512) sO[u] = obm[n * 1024 + u];
    __syncthreads();
    const float4* wp = (const float4*)(wfc + (size_t)t * 1024);
    float s = 0.f;
    for (int c4 = 0; c4 < 256; ++c4) {
      float4 w = wp[c4];
      s += w.x * sO[c4 * 4] + w.y * sO[c4 * 4 + 1] + w.z * sO[c4 * 4 + 2] + w.w * sO[c4 * 4 + 3];
    }
    out[n * 1024 + 512 + t] = fmaxf(s, 0.f);
    return;
  }
  const int n = blockIdx.x;
  const float* p = virt + (size_t)n * 25088 + t;
  float xv[49];
  float s1 = 0.f, s2 = 0.f;
  #pragma unroll
  for (int pp = 0; pp < 49; ++pp) {
    float x = p[pp * 512];
    xv[pp] = x; s1 += x; s2 += x * x;
  }
  __shared__ float r1[512], r2[512];
  r1[t] = s1; r2[t] = s2; __syncthreads();
  for (int off = 256; off; off >>= 1) {
    if (t < off) { r1[t] += r1[t + off]; r2[t] += r2[t + off]; }
    __syncthreads();
  }
  float mu = r1[0] * (1.f / 25088.f);
  float var = r2[0] * (1.f / 25088.f) - mu * mu;
  float rstd = rsqrtf(var + 1e-5f);
  float g = gamma[t], be = beta[t];
  const bf16* fp = f7b + (size_t)n * 25088 + t;
  float T = 0, R0 = 0, R6 = 0, C0 = 0, C6 = 0;
  float X00 = 0, X06 = 0, X60 = 0, X66 = 0, F = 0;
  #pragma unroll
  for (int pp = 0; pp < 49; ++pp) {
    const int u = pp / 7, v = pp - 7 * (pp / 7);
    float y = fmaxf((xv[pp] - mu) * rstd * g + be, 0.f);
    T += y;
    if (u == 0) R0 += y;
    if (u == 6) R6 += y;
    if (v == 0) C0 += y;
    if (v == 6) C6 += y;
    if (pp == 0)  X00 = y;
    if (pp == 6)  X06 = y;
    if (pp == 42) X60 = y;
    if (pp == 48) X66 = y;
    F += (float)fp[pp * 512];
  }
  float sv[9] = { T-R6-C6+X66, T-R6, T-R6-C0+X60,
                  T-C6,        T,    T-C0,
                  T-R0-C6+X06, T-R0, T-R0-C0+X00 };
  bf16* Ap = A_s + (size_t)n * 4608 + t;
  #pragma unroll
  for (int tap = 0; tap < 9; ++tap)
    Ap[tap * 512] = (bf16)(sv[tap] * (1.f / 49.f));
  out[n * 1024 + t] = F * (1.f / 49.f);   // base for gemm_s atomic adds
}

// ---------------------------------------------------------------------------
extern "C" void kernel_launch(void* const* d_in, const int* in_sizes, int n_in,
                              void* d_out, int out_size, void* d_ws, size_t ws_size,
                              hipStream_t stream) {
  const float* rois     = (const float*)d_in[0];
  const float* interact = (const float*)d_in[1];
  const float* bbox     = (const float*)d_in[2];
  const float* w_reduce = (const float*)d_in[3];
  const float* w_rsize  = (const float*)d_in[4];
  const float* wq       = (const float*)d_in[5];
  const float* wk       = (const float*)d_in[6];
  const float* wv       = (const float*)d_in[7];
  const float* w1       = (const float*)d_in[8];
  const float* gamma    = (const float*)d_in[9];
  const float* beta     = (const float*)d_in[10];
  const float* wfc      = (const float*)d_in[11];
  float* out = (float*)d_out;
  char* ws = (char*)d_ws;

  size_t o = 0;
  auto take = [&](size_t sz) { size_t r = o; o += (sz + 255) & ~(size_t)255; return r; };
  bf16*  wrb   = (bf16*)(ws + take(2359296));
  bf16*  wt    = (bf16*)(ws + take(18874368));
  bf16*  w1r   = (bf16*)(ws + take(4718592));
  char*  Rf1   = ws + take(33554432);
  bf16*  f7b   = (bf16*)(ws + take(6422528));
  float* virt  = (float*)(ws + take(12845056));
  bf16*  A_s   = (bf16*)(ws + take(1179648));
  float* obm   = (float*)(ws + take(524288));
  bf16*  zp    = (bf16*)(ws + take(256));
  size_t fixedEnd = o;
  const size_t A1_FULL = 150994944;
  bool full = (ws_size >= fixedEnd + A1_FULL);
  bf16* A1  = (bf16*)(ws + fixedEnd);
  bf16* f14 = (bf16*)(ws + fixedEnd);

  bf16* f1 = (bf16*)Rf1;
  bf16* qb = (bf16*)Rf1;
  bf16* kb = qb + 3211264;
  bf16* vb = kb + 3211264;

  hipMemsetAsync(zp, 0, 256, stream);

  k_wprep<<<6272, 256, 0, stream>>>(w_reduce, w_rsize, wq, wk, wv, w1, wrb, wt, w1r);

  if (full) {
    k_tin<<<dim3(36, 8, 128), 256, 0, stream>>>(interact, A1, 0);
    k_gemm_reduce<<<256, 512, 131072, stream>>>(A1, wrb, f1, 0);
  } else {
    for (int ch = 0; ch < 4; ++ch) {
      k_tin<<<dim3(36, 8, 32), 256, 0, stream>>>(interact, A1, ch * 32);
      k_gemm_reduce<<<64, 512, 131072, stream>>>(A1, wrb, f1, ch * 8192);
    }
  }

  k_conv_rsize<<<196, 512, 131072, stream>>>(f1, wt, f14);
  k_pool<<<6272, 256, 0, stream>>>(f14, f7b);

  // fused qkv convs (8-phase, blocks 0-149) + obm (150-1173)
  k_conv_qkv<<<1174, 512, 131072, stream>>>(f7b, wt + (size_t)1 * 2359296, qb, zp, bbox, obm);

  k_attn<<<dim3(49, 16), 256, 0, stream>>>(qb, kb, vb, rois, virt);

  k_ln_fc<<<256, 512, 0, stream>>>(virt, gamma, beta, f7b, A_s, obm, wfc, out);

  k_gemm_s<<<dim3(4, 4), 256, 0, stream>>>(A_s, w1r, out);
}